// Round 1
// baseline (2578.411 us; speedup 1.0000x reference)
//
#include <hip/hip_runtime.h>
#include <math.h>

#define NS 1024
#define ST 32
#define DF 158
#define DM 256
#define ROWS (NS*ST)           // 32768
#define SZ ((size_t)ROWS*DM)   // 8388608 floats = 32 MiB
#define LN_EPS 1e-5f

__device__ __forceinline__ float wave_sum(float v) {
#pragma unroll
    for (int o = 32; o > 0; o >>= 1) v += __shfl_xor(v, o);
    return v;
}

// ---------------- embed: h = x @ emb_w + emb_b + pe[t] ----------------
__global__ __launch_bounds__(256) void embed_k(const float* __restrict__ x,
        const float* __restrict__ W, const float* __restrict__ b,
        const float* __restrict__ pe, float* __restrict__ out) {
    int r = blockIdx.x;          // row in [0, 32768)
    int t = r & (ST - 1);
    int d = threadIdx.x;         // 0..255
    __shared__ float xs[DF];
    if (d < DF) xs[d] = x[(size_t)r*DF + d];
    __syncthreads();
    float acc = b[d] + pe[t*DM + d];
#pragma unroll 2
    for (int k = 0; k < DF; ++k) acc += xs[k] * W[(size_t)k*DM + d];
    out[(size_t)r*DM + d] = acc;
}

// ---------------- LayerNorm over last dim (optional fused add) ----------------
__global__ __launch_bounds__(256) void ln_k(const float* __restrict__ a,
        const float* __restrict__ bsrc, const float* __restrict__ g,
        const float* __restrict__ be, float* __restrict__ out) {
    int r = blockIdx.x, d = threadIdx.x;
    __shared__ float sb[4];
    size_t idx = (size_t)r*DM + d;
    float v = a[idx];
    if (bsrc) v += bsrc[idx];
    float s = wave_sum(v);
    if ((d & 63) == 0) sb[d >> 6] = s;
    __syncthreads();
    float mu = (sb[0]+sb[1]+sb[2]+sb[3]) * (1.0f/DM);
    __syncthreads();
    float c = v - mu;
    float s2 = wave_sum(c*c);
    if ((d & 63) == 0) sb[d >> 6] = s2;
    __syncthreads();
    float var = (sb[0]+sb[1]+sb[2]+sb[3]) * (1.0f/DM);
    out[idx] = c * rsqrtf(var + LN_EPS) * g[d] + be[d];
}

// ---------------- C[M,256] = A[M,256] @ W[256,256] (+bias)(+relu)(+resid) ----
__global__ __launch_bounds__(256) void gemm_k(const float* __restrict__ A,
        const float* __restrict__ W, const float* __restrict__ bias,
        const float* __restrict__ resid, float* __restrict__ C, int relu) {
    __shared__ float As[16][65];   // [k][m], padded
    __shared__ float Bs[16][64];   // [k][n]
    int tid = threadIdx.x;
    int tx = tid & 15, ty = tid >> 4;        // tx->n, ty->m
    const float* Ab = A + (size_t)blockIdx.x * 64 * DM;
    const float* Wb = W + blockIdx.y * 64;
    float acc[4][4] = {};
    int lr = tid >> 2, lc = (tid & 3) << 2;  // A tile loader
    int wr = tid >> 4, wc = (tid & 15) << 2; // W tile loader
    for (int k0 = 0; k0 < DM; k0 += 16) {
        float4 av = *(const float4*)(Ab + (size_t)lr*DM + k0 + lc);
        float4 wv = *(const float4*)(Wb + (size_t)(k0 + wr)*DM + wc);
        As[lc+0][lr] = av.x; As[lc+1][lr] = av.y;
        As[lc+2][lr] = av.z; As[lc+3][lr] = av.w;
        *(float4*)&Bs[wr][wc] = wv;
        __syncthreads();
#pragma unroll
        for (int kk = 0; kk < 16; ++kk) {
            float a0 = As[kk][ty*4+0], a1 = As[kk][ty*4+1];
            float a2 = As[kk][ty*4+2], a3 = As[kk][ty*4+3];
            float4 bv = *(const float4*)&Bs[kk][tx*4];
            acc[0][0] += a0*bv.x; acc[0][1] += a0*bv.y; acc[0][2] += a0*bv.z; acc[0][3] += a0*bv.w;
            acc[1][0] += a1*bv.x; acc[1][1] += a1*bv.y; acc[1][2] += a1*bv.z; acc[1][3] += a1*bv.w;
            acc[2][0] += a2*bv.x; acc[2][1] += a2*bv.y; acc[2][2] += a2*bv.z; acc[2][3] += a2*bv.w;
            acc[3][0] += a3*bv.x; acc[3][1] += a3*bv.y; acc[3][2] += a3*bv.z; acc[3][3] += a3*bv.w;
        }
        __syncthreads();
    }
    int n0 = blockIdx.y*64 + tx*4;
    float4 bz = make_float4(0.f, 0.f, 0.f, 0.f);
    if (bias) bz = *(const float4*)(bias + n0);
#pragma unroll
    for (int i = 0; i < 4; ++i) {
        size_t m = (size_t)blockIdx.x*64 + ty*4 + i;
        float4 o = make_float4(acc[i][0]+bz.x, acc[i][1]+bz.y,
                               acc[i][2]+bz.z, acc[i][3]+bz.w);
        if (relu) {
            o.x = fmaxf(o.x, 0.f); o.y = fmaxf(o.y, 0.f);
            o.z = fmaxf(o.z, 0.f); o.w = fmaxf(o.w, 0.f);
        }
        if (resid) {
            float4 rv = *(const float4*)(resid + m*DM + n0);
            o.x += rv.x; o.y += rv.y; o.z += rv.z; o.w += rv.w;
        }
        *(float4*)(C + m*DM + n0) = o;
    }
}

// ---------------- T-attention: per (head, stock), S=32, hd=64, scale=1.0 -----
__global__ __launch_bounds__(256) void attnT_k(const float* __restrict__ Q,
        const float* __restrict__ K, const float* __restrict__ V,
        float* __restrict__ O) {
    int h = blockIdx.x, n = blockIdx.y;
    __shared__ float qs[ST*64], ks[ST*64], vs[ST*64], ss[ST*33];
    int tid = threadIdx.x;
    size_t base = (size_t)n*ST*DM + h*64;
    for (int l = tid; l < ST*64; l += 256) {
        int i = l >> 6, d = l & 63;
        size_t gi = base + (size_t)i*DM + d;
        qs[l] = Q[gi]; ks[l] = K[gi]; vs[l] = V[gi];
    }
    __syncthreads();
    for (int e = tid; e < ST*ST; e += 256) {
        int i = e >> 5, j = e & 31;
        float s = 0.f;
#pragma unroll
        for (int d = 0; d < 64; ++d) s += qs[i*64+d]*ks[j*64+d];
        ss[i*33+j] = s;   // scale = 1.0 (source has no temperature on TAttention)
    }
    __syncthreads();
    if (tid < ST) {
        float mx = -1e30f;
        for (int j = 0; j < ST; ++j) mx = fmaxf(mx, ss[tid*33+j]);
        float sum = 0.f;
        for (int j = 0; j < ST; ++j) { float e = expf(ss[tid*33+j]-mx); ss[tid*33+j] = e; sum += e; }
        float inv = 1.0f/sum;
        for (int j = 0; j < ST; ++j) ss[tid*33+j] *= inv;
    }
    __syncthreads();
    for (int e = tid; e < ST*64; e += 256) {
        int i = e >> 6, d = e & 63;
        float o = 0.f;
#pragma unroll
        for (int j = 0; j < ST; ++j) o += ss[i*33+j]*vs[j*64+d];
        O[base + (size_t)i*DM + d] = o;
    }
}

// ---------------- S-attention: flash over 1024 stocks, scale=0.125 -----------
#define SP 65
#define VP 68
__global__ __launch_bounds__(256) void attnS_k(const float* __restrict__ Q,
        const float* __restrict__ K, const float* __restrict__ V,
        float* __restrict__ O) {
    __shared__ float Ks[64*SP];
    __shared__ float Vs[64*VP];
    __shared__ float Ps[64*SP];
    int qt = blockIdx.x, h = blockIdx.y, t = blockIdx.z;
    int tid = threadIdx.x;
    int qi = tid >> 2, sub = tid & 3;   // 4 lanes per q row; lanes consecutive
    size_t hoff = (size_t)t*DM + h*64;
    float4 qreg[16];
    {
        const float* qp = Q + (size_t)(qt*64 + qi)*ST*DM + hoff;
#pragma unroll
        for (int i = 0; i < 16; ++i) qreg[i] = *(const float4*)(qp + i*4);
    }
    float acc[16] = {};
    float m = -1e30f, l = 0.f;
    for (int kt = 0; kt < 16; ++kt) {
        __syncthreads();   // protect Ks/Vs/Ps from previous iteration readers
        for (int e = tid; e < 4096; e += 256) {
            int j = e >> 6, d = e & 63;
            size_t gi = (size_t)(kt*64 + j)*ST*DM + hoff + d;
            Ks[j*SP + d] = K[gi];
            Vs[j*VP + d] = V[gi];
        }
        __syncthreads();
        float sc[16];
        int j0 = sub*16;
#pragma unroll
        for (int jj = 0; jj < 16; ++jj) {
            const float* kr = Ks + (j0+jj)*SP;
            float s = 0.f;
#pragma unroll
            for (int i = 0; i < 16; ++i)
                s += qreg[i].x*kr[4*i+0] + qreg[i].y*kr[4*i+1]
                   + qreg[i].z*kr[4*i+2] + qreg[i].w*kr[4*i+3];
            sc[jj] = s * 0.125f;   // 1/sqrt(64)
        }
        float mt = sc[0];
#pragma unroll
        for (int jj = 1; jj < 16; ++jj) mt = fmaxf(mt, sc[jj]);
        mt = fmaxf(mt, __shfl_xor(mt, 1));
        mt = fmaxf(mt, __shfl_xor(mt, 2));
        float mn = fmaxf(m, mt);
        float alpha = expf(m - mn);
        float ls = 0.f;
#pragma unroll
        for (int jj = 0; jj < 16; ++jj) {
            float p = expf(sc[jj] - mn);
            Ps[qi*SP + j0 + jj] = p;
            ls += p;
        }
        ls += __shfl_xor(ls, 1);
        ls += __shfl_xor(ls, 2);
        l = l*alpha + ls;
        m = mn;
#pragma unroll
        for (int i = 0; i < 16; ++i) acc[i] *= alpha;
        __syncthreads();   // Ps visible to all 4 sub-lanes
        for (int j = 0; j < 64; ++j) {
            float p = Ps[qi*SP + j];
            const float4* vr = (const float4*)(Vs + j*VP + sub*16);
#pragma unroll
            for (int i = 0; i < 4; ++i) {
                float4 v4 = vr[i];
                acc[4*i+0] += p*v4.x; acc[4*i+1] += p*v4.y;
                acc[4*i+2] += p*v4.z; acc[4*i+3] += p*v4.w;
            }
        }
    }
    float inv = 1.0f / l;
    float* op = O + (size_t)(qt*64 + qi)*ST*DM + hoff + sub*16;
#pragma unroll
    for (int i = 0; i < 16; ++i) op[i] = acc[i]*inv;
}

// ---------------- temporal pooling + decoder ----------------
__global__ __launch_bounds__(256) void final_k(const float* __restrict__ H,
        const float* __restrict__ HH, const float* __restrict__ dw,
        const float* __restrict__ db, float* __restrict__ out) {
    int n = blockIdx.x, d = threadIdx.x;
    __shared__ float lam[ST];
    __shared__ float red[8];
    const float* hh = HH + (size_t)n*ST*DM;
    float qd = hh[31*DM + d];
    for (int t = 0; t < ST; ++t) {
        float v = wave_sum(hh[t*DM + d] * qd);
        if ((d & 63) == 0) red[d >> 6] = v;
        __syncthreads();
        if (d == 0) lam[t] = red[0]+red[1]+red[2]+red[3];
        __syncthreads();
    }
    float mx = -1e30f;
    for (int t = 0; t < ST; ++t) mx = fmaxf(mx, lam[t]);
    float sum = 0.f;
    for (int t = 0; t < ST; ++t) sum += expf(lam[t]-mx);
    float acc = 0.f;
    const float* hrow = H + (size_t)n*ST*DM;
    for (int t = 0; t < ST; ++t) acc += expf(lam[t]-mx) * hrow[t*DM + d];
    acc /= sum;   // pooled[d]
    float p0 = wave_sum(acc * dw[2*d+0]);
    float p1 = wave_sum(acc * dw[2*d+1]);
    if ((d & 63) == 0) { red[d >> 6] = p0; red[4 + (d >> 6)] = p1; }
    __syncthreads();
    if (d == 0) {
        float r0 = red[0]+red[1]+red[2]+red[3] + db[0];
        float r1 = red[4]+red[5]+red[6]+red[7] + db[1];
        out[(size_t)n*2+0] = r0;           out[(size_t)n*2+1] = r1;
        out[2048 + (size_t)n*2+0] = r0;    out[2048 + (size_t)n*2+1] = r1;
        out[4096 + (size_t)n*2+0] = r0;    out[4096 + (size_t)n*2+1] = r1;
        if (n == 0) out[6144] = 0.f;       // align_loss scalar
    }
}

extern "C" void kernel_launch(void* const* d_in, const int* in_sizes, int n_in,
                              void* d_out, int out_size, void* d_ws, size_t ws_size,
                              hipStream_t stream) {
    const float* x     = (const float*)d_in[0];
    const float* emb_w = (const float*)d_in[5];
    const float* emb_b = (const float*)d_in[6];
    const float* pe    = (const float*)d_in[7];
    const float* t_wq  = (const float*)d_in[8];
    const float* t_wk  = (const float*)d_in[9];
    const float* t_wv  = (const float*)d_in[10];
    const float* t_g1  = (const float*)d_in[11];
    const float* t_b1  = (const float*)d_in[12];
    const float* t_g2  = (const float*)d_in[13];
    const float* t_b2  = (const float*)d_in[14];
    const float* t_w1  = (const float*)d_in[15];
    const float* t_bb1 = (const float*)d_in[16];
    const float* t_w2  = (const float*)d_in[17];
    const float* t_bb2 = (const float*)d_in[18];
    const float* s_wq  = (const float*)d_in[19];
    const float* s_wk  = (const float*)d_in[20];
    const float* s_wv  = (const float*)d_in[21];
    const float* s_g1  = (const float*)d_in[22];
    const float* s_b1  = (const float*)d_in[23];
    const float* s_g2  = (const float*)d_in[24];
    const float* s_b2  = (const float*)d_in[25];
    const float* s_w1  = (const float*)d_in[26];
    const float* s_bb1 = (const float*)d_in[27];
    const float* s_w2  = (const float*)d_in[28];
    const float* s_bb2 = (const float*)d_in[29];
    const float* ta_w  = (const float*)d_in[30];
    const float* dec_w = (const float*)d_in[31];
    const float* dec_b = (const float*)d_in[32];
    float* out = (float*)d_out;

    float* B0 = (float*)d_ws;   // 5 ping-pong buffers, 32 MiB each
    float* B1 = B0 + SZ;
    float* B2 = B1 + SZ;
    float* B3 = B2 + SZ;
    float* B4 = B3 + SZ;

    dim3 gg(ROWS/64, 4);

    // ---- embed + PE ----
    embed_k<<<ROWS, 256, 0, stream>>>(x, emb_w, emb_b, pe, B0);          // B0 = h0
    // ---- TAttention block (over time) ----
    ln_k<<<ROWS, 256, 0, stream>>>(B0, nullptr, t_g1, t_b1, B1);         // B1 = xn
    gemm_k<<<gg, 256, 0, stream>>>(B1, t_wq, nullptr, nullptr, B2, 0);   // B2 = q
    gemm_k<<<gg, 256, 0, stream>>>(B1, t_wk, nullptr, nullptr, B3, 0);   // B3 = k
    gemm_k<<<gg, 256, 0, stream>>>(B1, t_wv, nullptr, nullptr, B4, 0);   // B4 = v
    attnT_k<<<dim3(4, NS), 256, 0, stream>>>(B2, B3, B4, B0);            // B0 = att
    ln_k<<<ROWS, 256, 0, stream>>>(B1, B0, t_g2, t_b2, B2);              // B2 = xt
    gemm_k<<<gg, 256, 0, stream>>>(B2, t_w1, t_bb1, nullptr, B3, 1);     // B3 = relu(xt@w1+b1)
    gemm_k<<<gg, 256, 0, stream>>>(B3, t_w2, t_bb2, B2, B4, 0);          // B4 = h1
    // ---- SAttention block (over stocks) ----
    ln_k<<<ROWS, 256, 0, stream>>>(B4, nullptr, s_g1, s_b1, B1);         // B1 = xn2
    gemm_k<<<gg, 256, 0, stream>>>(B1, s_wq, nullptr, nullptr, B2, 0);   // B2 = q
    gemm_k<<<gg, 256, 0, stream>>>(B1, s_wk, nullptr, nullptr, B3, 0);   // B3 = k
    gemm_k<<<gg, 256, 0, stream>>>(B1, s_wv, nullptr, nullptr, B0, 0);   // B0 = v
    attnS_k<<<dim3(16, 4, ST), 256, 0, stream>>>(B2, B3, B0, B4);        // B4 = att
    ln_k<<<ROWS, 256, 0, stream>>>(B1, B4, s_g2, s_b2, B2);              // B2 = xt2
    gemm_k<<<gg, 256, 0, stream>>>(B2, s_w1, s_bb1, nullptr, B3, 1);
    gemm_k<<<gg, 256, 0, stream>>>(B3, s_w2, s_bb2, B2, B1, 0);          // B1 = h2
    // ---- temporal attention + decoder ----
    gemm_k<<<gg, 256, 0, stream>>>(B1, ta_w, nullptr, nullptr, B0, 0);   // B0 = hh
    final_k<<<NS, 256, 0, stream>>>(B1, B0, dec_w, dec_b, out);
}

// Round 2
// 1307.602 us; speedup vs baseline: 1.9719x; 1.9719x over previous
//
#include <hip/hip_runtime.h>
#include <hip/hip_bf16.h>
#include <math.h>

#define NS 1024
#define ST 32
#define DF 158
#define DM 256
#define ROWS (NS*ST)           // 32768
#define SZ ((size_t)ROWS*DM)   // 8388608 floats = 32 MiB
#define LN_EPS 1e-5f

typedef __attribute__((ext_vector_type(8)))  __bf16 bf16x8;
typedef __attribute__((ext_vector_type(16))) float  f32x16;

__device__ __forceinline__ float wave_sum(float v) {
#pragma unroll
    for (int o = 32; o > 0; o >>= 1) v += __shfl_xor(v, o);
    return v;
}

__device__ __forceinline__ unsigned pkbf(float a, float b) {
    __hip_bfloat16 ha = __float2bfloat16(a), hb = __float2bfloat16(b);
    unsigned short ua, ub;
    __builtin_memcpy(&ua, &ha, 2); __builtin_memcpy(&ub, &hb, 2);
    return (unsigned)ua | ((unsigned)ub << 16);
}

// ---------------- embed: h = x @ emb_w + emb_b + pe[t] ----------------
__global__ __launch_bounds__(256) void embed_k(const float* __restrict__ x,
        const float* __restrict__ W, const float* __restrict__ b,
        const float* __restrict__ pe, float* __restrict__ out) {
    int r = blockIdx.x;          // row in [0, 32768)
    int t = r & (ST - 1);
    int d = threadIdx.x;         // 0..255
    __shared__ float xs[DF];
    if (d < DF) xs[d] = x[(size_t)r*DF + d];
    __syncthreads();
    float acc = b[d] + pe[t*DM + d];
#pragma unroll 2
    for (int k = 0; k < DF; ++k) acc += xs[k] * W[(size_t)k*DM + d];
    out[(size_t)r*DM + d] = acc;
}

// ---------------- LayerNorm over last dim (optional fused add) ----------------
__global__ __launch_bounds__(256) void ln_k(const float* __restrict__ a,
        const float* __restrict__ bsrc, const float* __restrict__ g,
        const float* __restrict__ be, float* __restrict__ out) {
    int r = blockIdx.x, d = threadIdx.x;
    __shared__ float sb[4];
    size_t idx = (size_t)r*DM + d;
    float v = a[idx];
    if (bsrc) v += bsrc[idx];
    float s = wave_sum(v);
    if ((d & 63) == 0) sb[d >> 6] = s;
    __syncthreads();
    float mu = (sb[0]+sb[1]+sb[2]+sb[3]) * (1.0f/DM);
    __syncthreads();
    float c = v - mu;
    float s2 = wave_sum(c*c);
    if ((d & 63) == 0) sb[d >> 6] = s2;
    __syncthreads();
    float var = (sb[0]+sb[1]+sb[2]+sb[3]) * (1.0f/DM);
    out[idx] = c * rsqrtf(var + LN_EPS) * g[d] + be[d];
}

// ---------------- C[M,256] = A[M,256] @ W[256,256] (+bias)(+relu)(+resid) ----
__global__ __launch_bounds__(256) void gemm_k(const float* __restrict__ A,
        const float* __restrict__ W, const float* __restrict__ bias,
        const float* __restrict__ resid, float* __restrict__ C, int relu) {
    __shared__ float As[16][65];   // [k][m], padded
    __shared__ float Bs[16][64];   // [k][n]
    int tid = threadIdx.x;
    int tx = tid & 15, ty = tid >> 4;        // tx->n, ty->m
    const float* Ab = A + (size_t)blockIdx.x * 64 * DM;
    const float* Wb = W + blockIdx.y * 64;
    float acc[4][4] = {};
    int lr = tid >> 2, lc = (tid & 3) << 2;  // A tile loader
    int wr = tid >> 4, wc = (tid & 15) << 2; // W tile loader
    for (int k0 = 0; k0 < DM; k0 += 16) {
        float4 av = *(const float4*)(Ab + (size_t)lr*DM + k0 + lc);
        float4 wv = *(const float4*)(Wb + (size_t)(k0 + wr)*DM + wc);
        As[lc+0][lr] = av.x; As[lc+1][lr] = av.y;
        As[lc+2][lr] = av.z; As[lc+3][lr] = av.w;
        *(float4*)&Bs[wr][wc] = wv;
        __syncthreads();
#pragma unroll
        for (int kk = 0; kk < 16; ++kk) {
            float a0 = As[kk][ty*4+0], a1 = As[kk][ty*4+1];
            float a2 = As[kk][ty*4+2], a3 = As[kk][ty*4+3];
            float4 bv = *(const float4*)&Bs[kk][tx*4];
            acc[0][0] += a0*bv.x; acc[0][1] += a0*bv.y; acc[0][2] += a0*bv.z; acc[0][3] += a0*bv.w;
            acc[1][0] += a1*bv.x; acc[1][1] += a1*bv.y; acc[1][2] += a1*bv.z; acc[1][3] += a1*bv.w;
            acc[2][0] += a2*bv.x; acc[2][1] += a2*bv.y; acc[2][2] += a2*bv.z; acc[2][3] += a2*bv.w;
            acc[3][0] += a3*bv.x; acc[3][1] += a3*bv.y; acc[3][2] += a3*bv.z; acc[3][3] += a3*bv.w;
        }
        __syncthreads();
    }
    int n0 = blockIdx.y*64 + tx*4;
    float4 bz = make_float4(0.f, 0.f, 0.f, 0.f);
    if (bias) bz = *(const float4*)(bias + n0);
#pragma unroll
    for (int i = 0; i < 4; ++i) {
        size_t m = (size_t)blockIdx.x*64 + ty*4 + i;
        float4 o = make_float4(acc[i][0]+bz.x, acc[i][1]+bz.y,
                               acc[i][2]+bz.z, acc[i][3]+bz.w);
        if (relu) {
            o.x = fmaxf(o.x, 0.f); o.y = fmaxf(o.y, 0.f);
            o.z = fmaxf(o.z, 0.f); o.w = fmaxf(o.w, 0.f);
        }
        if (resid) {
            float4 rv = *(const float4*)(resid + m*DM + n0);
            o.x += rv.x; o.y += rv.y; o.z += rv.z; o.w += rv.w;
        }
        *(float4*)(C + m*DM + n0) = o;
    }
}

// ---------------- T-attention: per (head, stock), S=32, hd=64, scale=1.0 -----
__global__ __launch_bounds__(256) void attnT_k(const float* __restrict__ Q,
        const float* __restrict__ K, const float* __restrict__ V,
        float* __restrict__ O) {
    int h = blockIdx.x, n = blockIdx.y;
    __shared__ float qs[ST*64], ks[ST*64], vs[ST*64], ss[ST*33];
    int tid = threadIdx.x;
    size_t base = (size_t)n*ST*DM + h*64;
    for (int l = tid; l < ST*64; l += 256) {
        int i = l >> 6, d = l & 63;
        size_t gi = base + (size_t)i*DM + d;
        qs[l] = Q[gi]; ks[l] = K[gi]; vs[l] = V[gi];
    }
    __syncthreads();
    for (int e = tid; e < ST*ST; e += 256) {
        int i = e >> 5, j = e & 31;
        float s = 0.f;
#pragma unroll
        for (int d = 0; d < 64; ++d) s += qs[i*64+d]*ks[j*64+d];
        ss[i*33+j] = s;   // scale = 1.0 (source has no temperature on TAttention)
    }
    __syncthreads();
    if (tid < ST) {
        float mx = -1e30f;
        for (int j = 0; j < ST; ++j) mx = fmaxf(mx, ss[tid*33+j]);
        float sum = 0.f;
        for (int j = 0; j < ST; ++j) { float e = expf(ss[tid*33+j]-mx); ss[tid*33+j] = e; sum += e; }
        float inv = 1.0f/sum;
        for (int j = 0; j < ST; ++j) ss[tid*33+j] *= inv;
    }
    __syncthreads();
    for (int e = tid; e < ST*64; e += 256) {
        int i = e >> 6, d = e & 63;
        float o = 0.f;
#pragma unroll
        for (int j = 0; j < ST; ++j) o += ss[i*33+j]*vs[j*64+d];
        O[base + (size_t)i*DM + d] = o;
    }
}

// ---------------- S-attention: MFMA bf16 flash over 1024 stocks --------------
// Per block: 128 q-rows for one (h, t). 4 waves, each owns a 32-q strip.
// S^T = K*Q^T per 64-stock K-tile -> softmax in-register -> O^T += V^T * P^T.
// Layout facts used (docs-verified): mfma_f32_32x32x16_bf16
//   A-frag: A[m=lane&31][k=(lane>>5)*8+j]   B-frag: B[k=(lane>>5)*8+j][n=lane&31]
//   C/D:    col(n)=lane&31, row(m)=(reg&3)+8*(reg>>2)+4*(lane>>5)
union __align__(16) LdsU {
    struct {
        __hip_bfloat16 K[64*72];   // K[stock][hd], row stride 72 (144B, 16B-aligned)
        __hip_bfloat16 Vt[64*72];  // Vt[hd][stock] (V transposed)
        __hip_bfloat16 Q[128*72];  // Q[q][hd]
    } s;
    float Ob[4][32*68];            // per-wave O^T transpose buffer (after loop)
};

__global__ __launch_bounds__(256) void attnS_k(const float* __restrict__ Qg,
        const float* __restrict__ Kg, const float* __restrict__ Vg,
        float* __restrict__ O) {
    __shared__ LdsU sm;
    const int qt = blockIdx.x;          // 0..7   (128-q tile)
    const int h  = blockIdx.y;          // 0..3
    const int tt = blockIdx.z;          // 0..31
    const int tid = threadIdx.x;
    const int w = tid >> 6, lane = tid & 63;
    const int uh = lane >> 5, l31 = lane & 31;
    const size_t hoff = (size_t)tt*DM + h*64;

    // ---- stage Q tile (128 x 64) as bf16 ----
#pragma unroll
    for (int p = 0; p < 8; ++p) {
        int r = p*16 + (tid >> 4);
        int c = (tid & 15) << 2;
        float4 v = *(const float4*)(Qg + (size_t)(qt*128 + r)*ST*DM + hoff + c);
        *(uint2*)&sm.s.Q[r*72 + c] = make_uint2(pkbf(v.x, v.y), pkbf(v.z, v.w));
    }
    __syncthreads();

    // ---- persistent Q^T B-fragments (k = hd dim) ----
    bf16x8 qf[4];
#pragma unroll
    for (int s = 0; s < 4; ++s)
        qf[s] = *(const bf16x8*)&sm.s.Q[(w*32 + l31)*72 + 16*s + 8*uh];

    f32x16 oa[2];
#pragma unroll
    for (int c = 0; c < 2; ++c)
#pragma unroll
        for (int r = 0; r < 16; ++r) oa[c][r] = 0.f;
    float mrun = -1e30f, lrun = 0.f;

    for (int kt = 0; kt < 16; ++kt) {
        __syncthreads();   // previous iteration's readers done
        // ---- stage K tile row-major ----
        {
            int j  = tid >> 2;
            int c0 = (tid & 3) << 4;
            const float* kr = Kg + (size_t)(kt*64 + j)*ST*DM + hoff + c0;
#pragma unroll
            for (int i = 0; i < 4; ++i) {
                float4 v = *(const float4*)(kr + 4*i);
                *(uint2*)&sm.s.K[j*72 + c0 + 4*i] = make_uint2(pkbf(v.x, v.y), pkbf(v.z, v.w));
            }
        }
        // ---- stage V tile transposed (Vt[d][stock]) ----
        {
            int j0 = (tid & 15) << 2;   // stock base
            int cb = (tid >> 4) << 2;   // hd base
            const float* vbp = Vg + (size_t)(kt*64 + j0)*ST*DM + hoff + cb;
            float4 r0 = *(const float4*)(vbp);
            float4 r1 = *(const float4*)(vbp + ST*DM);
            float4 r2 = *(const float4*)(vbp + 2*ST*DM);
            float4 r3 = *(const float4*)(vbp + 3*ST*DM);
            *(uint2*)&sm.s.Vt[(cb+0)*72 + j0] = make_uint2(pkbf(r0.x, r1.x), pkbf(r2.x, r3.x));
            *(uint2*)&sm.s.Vt[(cb+1)*72 + j0] = make_uint2(pkbf(r0.y, r1.y), pkbf(r2.y, r3.y));
            *(uint2*)&sm.s.Vt[(cb+2)*72 + j0] = make_uint2(pkbf(r0.z, r1.z), pkbf(r2.z, r3.z));
            *(uint2*)&sm.s.Vt[(cb+3)*72 + j0] = make_uint2(pkbf(r0.w, r1.w), pkbf(r2.w, r3.w));
        }
        __syncthreads();

        // ---- S^T tiles: [64 k x 32 q] = 2 x (32x32), chained over hd=64 ----
        f32x16 sa[2];
#pragma unroll
        for (int ct = 0; ct < 2; ++ct) {
            f32x16 acc;
#pragma unroll
            for (int r = 0; r < 16; ++r) acc[r] = 0.f;
            const __hip_bfloat16* kb = &sm.s.K[(ct*32 + l31)*72 + 8*uh];
            acc = __builtin_amdgcn_mfma_f32_32x32x16_bf16(*(const bf16x8*)(kb +  0), qf[0], acc, 0, 0, 0);
            acc = __builtin_amdgcn_mfma_f32_32x32x16_bf16(*(const bf16x8*)(kb + 16), qf[1], acc, 0, 0, 0);
            acc = __builtin_amdgcn_mfma_f32_32x32x16_bf16(*(const bf16x8*)(kb + 32), qf[2], acc, 0, 0, 0);
            acc = __builtin_amdgcn_mfma_f32_32x32x16_bf16(*(const bf16x8*)(kb + 48), qf[3], acc, 0, 0, 0);
            sa[ct] = acc;
        }

        // ---- online softmax (per-lane q column; halves joined via xor-32) ----
        float sc[32], p[32];
        float mloc = -1e30f;
#pragma unroll
        for (int ct = 0; ct < 2; ++ct)
#pragma unroll
            for (int r = 0; r < 16; ++r) {
                float v = sa[ct][r] * 0.125f;
                sc[ct*16 + r] = v;
                mloc = fmaxf(mloc, v);
            }
        mloc = fmaxf(mloc, __shfl_xor(mloc, 32));
        float mn = fmaxf(mrun, mloc);
        float alpha = __expf(mrun - mn);
        mrun = mn;
        float rs = 0.f;
#pragma unroll
        for (int i = 0; i < 32; ++i) { p[i] = __expf(sc[i] - mn); rs += p[i]; }
        rs += __shfl_xor(rs, 32);
        lrun = lrun*alpha + rs;
#pragma unroll
        for (int c = 0; c < 2; ++c)
#pragma unroll
            for (int r = 0; r < 16; ++r) oa[c][r] *= alpha;

        // ---- build P^T B-fragments from registers + xor-32 shuffles ----
        // frag[s]: k = 16*s + 8*uh + j ; ct = s>>1, base = 8*(s&1)
        bf16x8 bfr[4];
#pragma unroll
        for (int s = 0; s < 4; ++s) {
            int ct = s >> 1, b = (s & 1) << 3;
            unsigned pl0 = pkbf(p[ct*16+b+0], p[ct*16+b+1]);
            unsigned pl1 = pkbf(p[ct*16+b+2], p[ct*16+b+3]);
            unsigned ph0 = pkbf(p[ct*16+b+4], p[ct*16+b+5]);
            unsigned ph1 = pkbf(p[ct*16+b+6], p[ct*16+b+7]);
            unsigned ql0 = (unsigned)__shfl_xor((int)pl0, 32);
            unsigned ql1 = (unsigned)__shfl_xor((int)pl1, 32);
            unsigned qh0 = (unsigned)__shfl_xor((int)ph0, 32);
            unsigned qh1 = (unsigned)__shfl_xor((int)ph1, 32);
            unsigned w0 = uh ? qh0 : pl0;
            unsigned w1 = uh ? qh1 : pl1;
            unsigned w2 = uh ? ph0 : ql0;
            unsigned w3 = uh ? ph1 : ql1;
            union { uint4 i; bf16x8 v; } cv;
            cv.i = make_uint4(w0, w1, w2, w3);
            bfr[s] = cv.v;
        }

        // ---- O^T += V^T * P^T : 2 d-tiles, chained over k=64 ----
#pragma unroll
        for (int c = 0; c < 2; ++c) {
            const __hip_bfloat16* vb = &sm.s.Vt[(c*32 + l31)*72 + 8*uh];
            oa[c] = __builtin_amdgcn_mfma_f32_32x32x16_bf16(*(const bf16x8*)(vb +  0), bfr[0], oa[c], 0, 0, 0);
            oa[c] = __builtin_amdgcn_mfma_f32_32x32x16_bf16(*(const bf16x8*)(vb + 16), bfr[1], oa[c], 0, 0, 0);
            oa[c] = __builtin_amdgcn_mfma_f32_32x32x16_bf16(*(const bf16x8*)(vb + 32), bfr[2], oa[c], 0, 0, 0);
            oa[c] = __builtin_amdgcn_mfma_f32_32x32x16_bf16(*(const bf16x8*)(vb + 48), bfr[3], oa[c], 0, 0, 0);
        }
    }

    // ---- epilogue: transpose O^T via LDS, coalesced global store ----
    __syncthreads();   // all waves done reading K/Vt/Q
    float invl = 1.0f / lrun;
    float* ob = sm.Ob[w];
#pragma unroll
    for (int c = 0; c < 2; ++c)
#pragma unroll
        for (int r = 0; r < 16; ++r) {
            int d = (r & 3) + ((r >> 2) << 3) + 4*uh + 32*c;
            ob[l31*68 + d] = oa[c][r] * invl;
        }
    // wave-local read-back (no barrier needed)
#pragma unroll
    for (int pp = 0; pp < 2; ++pp) {
        int qr = pp*16 + (lane >> 2);
        int dc = (lane & 3) << 4;
        float* gp = O + (size_t)(qt*128 + w*32 + qr)*ST*DM + hoff + dc;
#pragma unroll
        for (int i = 0; i < 4; ++i)
            *(float4*)(gp + 4*i) = *(const float4*)&ob[qr*68 + dc + 4*i];
    }
}

// ---------------- temporal pooling + decoder ----------------
__global__ __launch_bounds__(256) void final_k(const float* __restrict__ H,
        const float* __restrict__ HH, const float* __restrict__ dw,
        const float* __restrict__ db, float* __restrict__ out) {
    int n = blockIdx.x, d = threadIdx.x;
    __shared__ float lam[ST];
    __shared__ float red[8];
    const float* hh = HH + (size_t)n*ST*DM;
    float qd = hh[31*DM + d];
    for (int t = 0; t < ST; ++t) {
        float v = wave_sum(hh[t*DM + d] * qd);
        if ((d & 63) == 0) red[d >> 6] = v;
        __syncthreads();
        if (d == 0) lam[t] = red[0]+red[1]+red[2]+red[3];
        __syncthreads();
    }
    float mx = -1e30f;
    for (int t = 0; t < ST; ++t) mx = fmaxf(mx, lam[t]);
    float sum = 0.f;
    for (int t = 0; t < ST; ++t) sum += expf(lam[t]-mx);
    float acc = 0.f;
    const float* hrow = H + (size_t)n*ST*DM;
    for (int t = 0; t < ST; ++t) acc += expf(lam[t]-mx) * hrow[t*DM + d];
    acc /= sum;   // pooled[d]
    float p0 = wave_sum(acc * dw[2*d+0]);
    float p1 = wave_sum(acc * dw[2*d+1]);
    if ((d & 63) == 0) { red[d >> 6] = p0; red[4 + (d >> 6)] = p1; }
    __syncthreads();
    if (d == 0) {
        float r0 = red[0]+red[1]+red[2]+red[3] + db[0];
        float r1 = red[4]+red[5]+red[6]+red[7] + db[1];
        out[(size_t)n*2+0] = r0;           out[(size_t)n*2+1] = r1;
        out[2048 + (size_t)n*2+0] = r0;    out[2048 + (size_t)n*2+1] = r1;
        out[4096 + (size_t)n*2+0] = r0;    out[4096 + (size_t)n*2+1] = r1;
        if (n == 0) out[6144] = 0.f;       // align_loss scalar
    }
}

extern "C" void kernel_launch(void* const* d_in, const int* in_sizes, int n_in,
                              void* d_out, int out_size, void* d_ws, size_t ws_size,
                              hipStream_t stream) {
    const float* x     = (const float*)d_in[0];
    const float* emb_w = (const float*)d_in[5];
    const float* emb_b = (const float*)d_in[6];
    const float* pe    = (const float*)d_in[7];
    const float* t_wq  = (const float*)d_in[8];
    const float* t_wk  = (const float*)d_in[9];
    const float* t_wv  = (const float*)d_in[10];
    const float* t_g1  = (const float*)d_in[11];
    const float* t_b1  = (const float*)d_in[12];
    const float* t_g2  = (const float*)d_in[13];
    const float* t_b2  = (const float*)d_in[14];
    const float* t_w1  = (const float*)d_in[15];
    const float* t_bb1 = (const float*)d_in[16];
    const float* t_w2  = (const float*)d_in[17];
    const float* t_bb2 = (const float*)d_in[18];
    const float* s_wq  = (const float*)d_in[19];
    const float* s_wk  = (const float*)d_in[20];
    const float* s_wv  = (const float*)d_in[21];
    const float* s_g1  = (const float*)d_in[22];
    const float* s_b1  = (const float*)d_in[23];
    const float* s_g2  = (const float*)d_in[24];
    const float* s_b2  = (const float*)d_in[25];
    const float* s_w1  = (const float*)d_in[26];
    const float* s_bb1 = (const float*)d_in[27];
    const float* s_w2  = (const float*)d_in[28];
    const float* s_bb2 = (const float*)d_in[29];
    const float* ta_w  = (const float*)d_in[30];
    const float* dec_w = (const float*)d_in[31];
    const float* dec_b = (const float*)d_in[32];
    float* out = (float*)d_out;

    float* B0 = (float*)d_ws;   // 5 ping-pong buffers, 32 MiB each
    float* B1 = B0 + SZ;
    float* B2 = B1 + SZ;
    float* B3 = B2 + SZ;
    float* B4 = B3 + SZ;

    dim3 gg(ROWS/64, 4);

    // ---- embed + PE ----
    embed_k<<<ROWS, 256, 0, stream>>>(x, emb_w, emb_b, pe, B0);          // B0 = h0
    // ---- TAttention block (over time) ----
    ln_k<<<ROWS, 256, 0, stream>>>(B0, nullptr, t_g1, t_b1, B1);         // B1 = xn
    gemm_k<<<gg, 256, 0, stream>>>(B1, t_wq, nullptr, nullptr, B2, 0);   // B2 = q
    gemm_k<<<gg, 256, 0, stream>>>(B1, t_wk, nullptr, nullptr, B3, 0);   // B3 = k
    gemm_k<<<gg, 256, 0, stream>>>(B1, t_wv, nullptr, nullptr, B4, 0);   // B4 = v
    attnT_k<<<dim3(4, NS), 256, 0, stream>>>(B2, B3, B4, B0);            // B0 = att
    ln_k<<<ROWS, 256, 0, stream>>>(B1, B0, t_g2, t_b2, B2);              // B2 = xt
    gemm_k<<<gg, 256, 0, stream>>>(B2, t_w1, t_bb1, nullptr, B3, 1);     // B3 = relu(xt@w1+b1)
    gemm_k<<<gg, 256, 0, stream>>>(B3, t_w2, t_bb2, B2, B4, 0);          // B4 = h1
    // ---- SAttention block (over stocks) ----
    ln_k<<<ROWS, 256, 0, stream>>>(B4, nullptr, s_g1, s_b1, B1);         // B1 = xn2
    gemm_k<<<gg, 256, 0, stream>>>(B1, s_wq, nullptr, nullptr, B2, 0);   // B2 = q
    gemm_k<<<gg, 256, 0, stream>>>(B1, s_wk, nullptr, nullptr, B3, 0);   // B3 = k
    gemm_k<<<gg, 256, 0, stream>>>(B1, s_wv, nullptr, nullptr, B0, 0);   // B0 = v
    attnS_k<<<dim3(8, 4, ST), 256, 0, stream>>>(B2, B3, B0, B4);         // B4 = att
    ln_k<<<ROWS, 256, 0, stream>>>(B1, B4, s_g2, s_b2, B2);              // B2 = xt2
    gemm_k<<<gg, 256, 0, stream>>>(B2, s_w1, s_bb1, nullptr, B3, 1);
    gemm_k<<<gg, 256, 0, stream>>>(B3, s_w2, s_bb2, B2, B1, 0);          // B1 = h2
    // ---- temporal attention + decoder ----
    gemm_k<<<gg, 256, 0, stream>>>(B1, ta_w, nullptr, nullptr, B0, 0);   // B0 = hh
    final_k<<<NS, 256, 0, stream>>>(B1, B0, dec_w, dec_b, out);
}

// Round 4
// 771.358 us; speedup vs baseline: 3.3427x; 1.6952x over previous
//
#include <hip/hip_runtime.h>
#include <hip/hip_bf16.h>
#include <math.h>

#define NS 1024
#define ST 32
#define DF 158
#define DM 256
#define ROWS (NS*ST)           // 32768
#define SZ ((size_t)ROWS*DM)   // 8388608 elems
#define LN_EPS 1e-5f

typedef __attribute__((ext_vector_type(8)))  __bf16 bf16x8;
typedef __attribute__((ext_vector_type(16))) float  f32x16;

__device__ __forceinline__ float wave_sum(float v) {
#pragma unroll
    for (int o = 32; o > 0; o >>= 1) v += __shfl_xor(v, o);
    return v;
}

__device__ __forceinline__ unsigned pkbf(float a, float b) {
    __hip_bfloat16 ha = __float2bfloat16(a), hb = __float2bfloat16(b);
    unsigned short ua, ub;
    __builtin_memcpy(&ua, &ha, 2); __builtin_memcpy(&ub, &hb, 2);
    return (unsigned)ua | ((unsigned)ub << 16);
}

__device__ __forceinline__ float2 bf2x(unsigned u) {
    union { unsigned i; float f; } a, b;
    a.i = u << 16; b.i = u & 0xffff0000u;
    return make_float2(a.f, b.f);
}

// ================= conversion kernels (run every launch; idempotent) =========
__global__ __launch_bounds__(256) void cvtx_k(const float* __restrict__ x,
        __hip_bfloat16* __restrict__ xb) {
    int idx = blockIdx.x*256 + threadIdx.x;          // < 32768*160
    int r = idx / 160, c = idx - r*160;
    float v = (c < DF) ? x[(size_t)r*DF + c] : 0.f;
    xb[idx] = __float2bfloat16(v);
}

struct WPack { const float* s[11]; __hip_bfloat16* d[11]; };

__global__ __launch_bounds__(256) void cvtw_k(WPack wp) {
    const float* W = wp.s[blockIdx.z];
    __hip_bfloat16* Wt = wp.d[blockIdx.z];
    __shared__ float t[64][65];
    int bi = blockIdx.x*64, bj = blockIdx.y*64;
    int r = threadIdx.x >> 2, c0 = (threadIdx.x & 3) * 16;
#pragma unroll
    for (int i = 0; i < 16; i += 4) {
        float4 v = *(const float4*)(W + (size_t)(bi + r)*DM + bj + c0 + i);
        t[r][c0+i+0] = v.x; t[r][c0+i+1] = v.y;
        t[r][c0+i+2] = v.z; t[r][c0+i+3] = v.w;
    }
    __syncthreads();
    // Wt[n][k]: n = bj + r, k = bi + c0 .. c0+15
    unsigned u[8];
#pragma unroll
    for (int i = 0; i < 8; ++i) u[i] = pkbf(t[c0+2*i][r], t[c0+2*i+1][r]);
    __hip_bfloat16* op = Wt + (size_t)(bj + r)*DM + bi + c0;
    *(uint4*)(op)     = make_uint4(u[0], u[1], u[2], u[3]);
    *(uint4*)(op + 8) = make_uint4(u[4], u[5], u[6], u[7]);
}

__global__ __launch_bounds__(192) void cvte_k(const float* __restrict__ W,
        __hip_bfloat16* __restrict__ Wt) {
    int n = blockIdx.x, t = threadIdx.x;
    if (t < 160) {
        float v = (t < DF) ? W[(size_t)t*DM + n] : 0.f;
        Wt[(size_t)n*160 + t] = __float2bfloat16(v);
    }
}

// ================= LayerNorm: fp32 in -> fp32 + bf16 out =====================
__global__ __launch_bounds__(256) void ln_k(const float* __restrict__ a,
        const float* __restrict__ g, const float* __restrict__ be,
        float* __restrict__ out, __hip_bfloat16* __restrict__ outb) {
    int r = blockIdx.x, d = threadIdx.x;
    __shared__ float sb[4];
    size_t idx = (size_t)r*DM + d;
    float v = a[idx];
    float s = wave_sum(v);
    if ((d & 63) == 0) sb[d >> 6] = s;
    __syncthreads();
    float mu = (sb[0]+sb[1]+sb[2]+sb[3]) * (1.0f/DM);
    __syncthreads();
    float c = v - mu;
    float s2 = wave_sum(c*c);
    if ((d & 63) == 0) sb[d >> 6] = s2;
    __syncthreads();
    float var = (sb[0]+sb[1]+sb[2]+sb[3]) * (1.0f/DM);
    float o = c * rsqrtf(var + LN_EPS) * g[d] + be[d];
    out[idx] = o;
    outb[idx] = __float2bfloat16(o);
}

// ================= MFMA GEMM: C[M,256] = A[M,K]@W[K,256] =====================
// A bf16 row-major (stride sA), Wt bf16 TRANSPOSED [256][K] (stride sW).
// 128x128 block tile, BK=32, 4 waves in 2x2, each 2x2 of 32x32x16 MFMA.
__global__ __launch_bounds__(256) void mgemm_k(const __hip_bfloat16* __restrict__ A,
        int sA, int nk, const __hip_bfloat16* __restrict__ Wt, int sW,
        const float* __restrict__ bias, const float* __restrict__ pe,
        const float* __restrict__ resid, float* __restrict__ Cf,
        __hip_bfloat16* __restrict__ Cb, int relu) {
    __shared__ __hip_bfloat16 As[128*40];
    __shared__ __hip_bfloat16 Ws[128*40];
    const int tid = threadIdx.x;
    const int w = tid >> 6, lane = tid & 63;
    const int uh = lane >> 5, l31 = lane & 31;
    const int wm = (w >> 1) * 64, wn = (w & 1) * 64;
    const size_t m0 = (size_t)blockIdx.x * 128;
    const int n0 = blockIdx.y * 128;

    f32x16 acc[2][2];
#pragma unroll
    for (int mt = 0; mt < 2; ++mt)
#pragma unroll
        for (int nt = 0; nt < 2; ++nt)
#pragma unroll
            for (int r = 0; r < 16; ++r) acc[mt][nt][r] = 0.f;

    // staging: 128 rows x 32 k per matrix; 256 threads x 2 uint4 each
    const int lr = tid >> 1;          // 0..127
    const int lc = (tid & 1) * 16;    // 0 or 16
    for (int kt = 0; kt < nk; ++kt) {
        __syncthreads();
        const __hip_bfloat16* ap = A  + (m0 + lr)*sA + kt*32 + lc;
        const __hip_bfloat16* wp = Wt + (size_t)(n0 + lr)*sW + kt*32 + lc;
        *(uint4*)&As[lr*40 + lc]     = *(const uint4*)(ap);
        *(uint4*)&As[lr*40 + lc + 8] = *(const uint4*)(ap + 8);
        *(uint4*)&Ws[lr*40 + lc]     = *(const uint4*)(wp);
        *(uint4*)&Ws[lr*40 + lc + 8] = *(const uint4*)(wp + 8);
        __syncthreads();
        bf16x8 af[2][2], bg[2][2];
#pragma unroll
        for (int mt = 0; mt < 2; ++mt)
#pragma unroll
            for (int ks = 0; ks < 2; ++ks)
                af[mt][ks] = *(const bf16x8*)&As[(wm + mt*32 + l31)*40 + ks*16 + uh*8];
#pragma unroll
        for (int nt = 0; nt < 2; ++nt)
#pragma unroll
            for (int ks = 0; ks < 2; ++ks)
                bg[nt][ks] = *(const bf16x8*)&Ws[(wn + nt*32 + l31)*40 + ks*16 + uh*8];
#pragma unroll
        for (int mt = 0; mt < 2; ++mt)
#pragma unroll
            for (int nt = 0; nt < 2; ++nt) {
                acc[mt][nt] = __builtin_amdgcn_mfma_f32_32x32x16_bf16(af[mt][0], bg[nt][0], acc[mt][nt], 0, 0, 0);
                acc[mt][nt] = __builtin_amdgcn_mfma_f32_32x32x16_bf16(af[mt][1], bg[nt][1], acc[mt][nt], 0, 0, 0);
            }
    }

#pragma unroll
    for (int nt = 0; nt < 2; ++nt) {
        int colg = n0 + wn + nt*32 + l31;
        float bz = bias ? bias[colg] : 0.f;
#pragma unroll
        for (int mt = 0; mt < 2; ++mt) {
#pragma unroll
            for (int r = 0; r < 16; ++r) {
                size_t mg = m0 + wm + mt*32 + (r & 3) + ((r >> 2) << 3) + 4*uh;
                float v = acc[mt][nt][r] + bz;
                if (pe)    v += pe[(mg & 31)*DM + colg];
                if (relu)  v = fmaxf(v, 0.f);
                if (resid) v += resid[mg*DM + colg];
                if (Cf) Cf[mg*DM + colg] = v;
                if (Cb) Cb[mg*DM + colg] = __float2bfloat16(v);
            }
        }
    }
}

// ================= T-attention (bf16 in, fused resid add into O) =============
__global__ __launch_bounds__(256) void attnT_k(const __hip_bfloat16* __restrict__ Q,
        const __hip_bfloat16* __restrict__ K, const __hip_bfloat16* __restrict__ V,
        float* __restrict__ O) {
    int h = blockIdx.x, n = blockIdx.y;
    __shared__ float qs[ST*64], ks[ST*64], vs[ST*64], ss[ST*33];
    int tid = threadIdx.x;
    size_t base = (size_t)n*ST*DM + h*64;       // elements
    for (int p = tid; p < ST*32; p += 256) {
        int i = p >> 5, dp = (p & 31) * 2;
        size_t gi = base + (size_t)i*DM + dp;
        float2 q2 = bf2x(*(const unsigned*)(Q + gi));
        float2 k2 = bf2x(*(const unsigned*)(K + gi));
        float2 v2 = bf2x(*(const unsigned*)(V + gi));
        qs[i*64+dp] = q2.x; qs[i*64+dp+1] = q2.y;
        ks[i*64+dp] = k2.x; ks[i*64+dp+1] = k2.y;
        vs[i*64+dp] = v2.x; vs[i*64+dp+1] = v2.y;
    }
    __syncthreads();
    for (int e = tid; e < ST*ST; e += 256) {
        int i = e >> 5, j = e & 31;
        float s = 0.f;
#pragma unroll
        for (int d = 0; d < 64; ++d) s += qs[i*64+d]*ks[j*64+d];
        ss[i*33+j] = s;   // scale = 1.0 (no temperature on TAttention)
    }
    __syncthreads();
    if (tid < ST) {
        float mx = -1e30f;
        for (int j = 0; j < ST; ++j) mx = fmaxf(mx, ss[tid*33+j]);
        float sum = 0.f;
        for (int j = 0; j < ST; ++j) { float e = expf(ss[tid*33+j]-mx); ss[tid*33+j] = e; sum += e; }
        float inv = 1.0f/sum;
        for (int j = 0; j < ST; ++j) ss[tid*33+j] *= inv;
    }
    __syncthreads();
    for (int e = tid; e < ST*64; e += 256) {
        int i = e >> 6, d = e & 63;
        float o = 0.f;
#pragma unroll
        for (int j = 0; j < ST; ++j) o += ss[i*33+j]*vs[j*64+d];
        O[base + (size_t)i*DM + d] += o;        // fused residual add
    }
}

// ================= S-attention: MFMA bf16 flash, fused resid add =============
union __align__(16) LdsS {
    struct {
        __hip_bfloat16 K[64*72];   // K[stock][hd]
        __hip_bfloat16 Vt[64*72];  // Vt[hd][stock]
    } s;
    float Ob[4][32*68];            // per-wave O^T transpose buffer (epilogue)
};

__global__ __launch_bounds__(256) void attnS_k(const __hip_bfloat16* __restrict__ Qb,
        const __hip_bfloat16* __restrict__ Kb, const __hip_bfloat16* __restrict__ Vb,
        float* __restrict__ O) {
    __shared__ LdsS sm;
    const int qt = blockIdx.x, h = blockIdx.y, tt = blockIdx.z;
    const int tid = threadIdx.x;
    const int w = tid >> 6, lane = tid & 63;
    const int uh = lane >> 5, l31 = lane & 31;
    const size_t hoff = (size_t)tt*DM + h*64;

    // Q^T B-fragments straight from global (rows are contiguous bf16)
    bf16x8 qf[4];
    {
        const __hip_bfloat16* qp = Qb + (size_t)(qt*128 + w*32 + l31)*ST*DM + hoff + 8*uh;
        qf[0] = *(const bf16x8*)(qp);
        qf[1] = *(const bf16x8*)(qp + 16);
        qf[2] = *(const bf16x8*)(qp + 32);
        qf[3] = *(const bf16x8*)(qp + 48);
    }

    f32x16 oa[2];
#pragma unroll
    for (int c = 0; c < 2; ++c)
#pragma unroll
        for (int r = 0; r < 16; ++r) oa[c][r] = 0.f;
    float mrun = -1e30f, lrun = 0.f;

    for (int kt = 0; kt < 16; ++kt) {
        __syncthreads();
        // stage K row-major: 64 rows x 8 chunks of 8 bf16
#pragma unroll
        for (int p = 0; p < 2; ++p) {
            int idx = p*256 + tid;
            int j = idx >> 3, c = (idx & 7) * 8;
            *(uint4*)&sm.s.K[j*72 + c] =
                *(const uint4*)(Kb + (size_t)(kt*64 + j)*ST*DM + hoff + c);
        }
        // stage V transposed
        {
            int j0 = (tid & 15) * 4, cb = (tid >> 4) * 4;
            const ushort* vp = (const ushort*)(Vb + (size_t)(kt*64 + j0)*ST*DM + hoff + cb);
            ushort4 s0 = *(const ushort4*)(vp);
            ushort4 s1 = *(const ushort4*)(vp + ST*DM);
            ushort4 s2 = *(const ushort4*)(vp + 2*ST*DM);
            ushort4 s3 = *(const ushort4*)(vp + 3*ST*DM);
            *(uint2*)&sm.s.Vt[(cb+0)*72 + j0] = make_uint2((unsigned)s0.x | ((unsigned)s1.x<<16),
                                                           (unsigned)s2.x | ((unsigned)s3.x<<16));
            *(uint2*)&sm.s.Vt[(cb+1)*72 + j0] = make_uint2((unsigned)s0.y | ((unsigned)s1.y<<16),
                                                           (unsigned)s2.y | ((unsigned)s3.y<<16));
            *(uint2*)&sm.s.Vt[(cb+2)*72 + j0] = make_uint2((unsigned)s0.z | ((unsigned)s1.z<<16),
                                                           (unsigned)s2.z | ((unsigned)s3.z<<16));
            *(uint2*)&sm.s.Vt[(cb+3)*72 + j0] = make_uint2((unsigned)s0.w | ((unsigned)s1.w<<16),
                                                           (unsigned)s2.w | ((unsigned)s3.w<<16));
        }
        __syncthreads();

        // S^T = K * Q^T : 2 x (32x32), chained over hd=64
        f32x16 sa[2];
#pragma unroll
        for (int ct = 0; ct < 2; ++ct) {
            f32x16 a2;
#pragma unroll
            for (int r = 0; r < 16; ++r) a2[r] = 0.f;
            const __hip_bfloat16* kb = &sm.s.K[(ct*32 + l31)*72 + 8*uh];
            a2 = __builtin_amdgcn_mfma_f32_32x32x16_bf16(*(const bf16x8*)(kb +  0), qf[0], a2, 0, 0, 0);
            a2 = __builtin_amdgcn_mfma_f32_32x32x16_bf16(*(const bf16x8*)(kb + 16), qf[1], a2, 0, 0, 0);
            a2 = __builtin_amdgcn_mfma_f32_32x32x16_bf16(*(const bf16x8*)(kb + 32), qf[2], a2, 0, 0, 0);
            a2 = __builtin_amdgcn_mfma_f32_32x32x16_bf16(*(const bf16x8*)(kb + 48), qf[3], a2, 0, 0, 0);
            sa[ct] = a2;
        }

        // online softmax (per-lane q column; halves joined via xor-32)
        float sc[32], p[32];
        float mloc = -1e30f;
#pragma unroll
        for (int ct = 0; ct < 2; ++ct)
#pragma unroll
            for (int r = 0; r < 16; ++r) {
                float v = sa[ct][r] * 0.125f;
                sc[ct*16 + r] = v;
                mloc = fmaxf(mloc, v);
            }
        mloc = fmaxf(mloc, __shfl_xor(mloc, 32));
        float mn = fmaxf(mrun, mloc);
        float alpha = __expf(mrun - mn);
        mrun = mn;
        float rs = 0.f;
#pragma unroll
        for (int i = 0; i < 32; ++i) { p[i] = __expf(sc[i] - mn); rs += p[i]; }
        rs += __shfl_xor(rs, 32);
        lrun = lrun*alpha + rs;
#pragma unroll
        for (int c = 0; c < 2; ++c)
#pragma unroll
            for (int r = 0; r < 16; ++r) oa[c][r] *= alpha;

        // P^T B-fragments from registers + xor-32 shuffles
        bf16x8 bfr[4];
#pragma unroll
        for (int s = 0; s < 4; ++s) {
            int ct = s >> 1, b = (s & 1) << 3;
            unsigned pl0 = pkbf(p[ct*16+b+0], p[ct*16+b+1]);
            unsigned pl1 = pkbf(p[ct*16+b+2], p[ct*16+b+3]);
            unsigned ph0 = pkbf(p[ct*16+b+4], p[ct*16+b+5]);
            unsigned ph1 = pkbf(p[ct*16+b+6], p[ct*16+b+7]);
            unsigned ql0 = (unsigned)__shfl_xor((int)pl0, 32);
            unsigned ql1 = (unsigned)__shfl_xor((int)pl1, 32);
            unsigned qh0 = (unsigned)__shfl_xor((int)ph0, 32);
            unsigned qh1 = (unsigned)__shfl_xor((int)ph1, 32);
            unsigned w0 = uh ? qh0 : pl0;
            unsigned w1 = uh ? qh1 : pl1;
            unsigned w2 = uh ? ph0 : ql0;
            unsigned w3 = uh ? ph1 : ql1;
            union { uint4 i; bf16x8 v; } cv;
            cv.i = make_uint4(w0, w1, w2, w3);
            bfr[s] = cv.v;
        }

        // O^T += V^T * P^T
#pragma unroll
        for (int c = 0; c < 2; ++c) {
            const __hip_bfloat16* vb = &sm.s.Vt[(c*32 + l31)*72 + 8*uh];
            oa[c] = __builtin_amdgcn_mfma_f32_32x32x16_bf16(*(const bf16x8*)(vb +  0), bfr[0], oa[c], 0, 0, 0);
            oa[c] = __builtin_amdgcn_mfma_f32_32x32x16_bf16(*(const bf16x8*)(vb + 16), bfr[1], oa[c], 0, 0, 0);
            oa[c] = __builtin_amdgcn_mfma_f32_32x32x16_bf16(*(const bf16x8*)(vb + 32), bfr[2], oa[c], 0, 0, 0);
            oa[c] = __builtin_amdgcn_mfma_f32_32x32x16_bf16(*(const bf16x8*)(vb + 48), bfr[3], oa[c], 0, 0, 0);
        }
    }

    // epilogue: transpose O^T via LDS, fused residual add, coalesced store
    __syncthreads();
    float invl = 1.0f / lrun;
    float* ob = sm.Ob[w];
#pragma unroll
    for (int c = 0; c < 2; ++c)
#pragma unroll
        for (int r = 0; r < 16; ++r) {
            int d = (r & 3) + ((r >> 2) << 3) + 4*uh + 32*c;
            ob[l31*68 + d] = oa[c][r] * invl;
        }
#pragma unroll
    for (int pp = 0; pp < 2; ++pp) {
        int qr = pp*16 + (lane >> 2);
        int dc = (lane & 3) << 4;
        float* gp = O + (size_t)(qt*128 + w*32 + qr)*ST*DM + hoff + dc;
#pragma unroll
        for (int i = 0; i < 4; ++i) {
            float4 prev = *(const float4*)(gp + 4*i);
            float4 nv = *(const float4*)&ob[qr*68 + dc + 4*i];
            *(float4*)(gp + 4*i) = make_float4(prev.x+nv.x, prev.y+nv.y,
                                               prev.z+nv.z, prev.w+nv.w);
        }
    }
}

// ================= temporal pooling + decoder ================================
__global__ __launch_bounds__(256) void final_k(const float* __restrict__ H,
        const float* __restrict__ HH, const float* __restrict__ dw,
        const float* __restrict__ db, float* __restrict__ out) {
    int n = blockIdx.x, d = threadIdx.x;
    __shared__ float lam[ST];
    __shared__ float red[8];
    const float* hh = HH + (size_t)n*ST*DM;
    float qd = hh[31*DM + d];
    for (int t = 0; t < ST; ++t) {
        float v = wave_sum(hh[t*DM + d] * qd);
        if ((d & 63) == 0) red[d >> 6] = v;
        __syncthreads();
        if (d == 0) lam[t] = red[0]+red[1]+red[2]+red[3];
        __syncthreads();
    }
    float mx = -1e30f;
    for (int t = 0; t < ST; ++t) mx = fmaxf(mx, lam[t]);
    float sum = 0.f;
    for (int t = 0; t < ST; ++t) sum += expf(lam[t]-mx);
    float acc = 0.f;
    const float* hrow = H + (size_t)n*ST*DM;
    for (int t = 0; t < ST; ++t) acc += expf(lam[t]-mx) * hrow[t*DM + d];
    acc /= sum;
    float p0 = wave_sum(acc * dw[2*d+0]);
    float p1 = wave_sum(acc * dw[2*d+1]);
    if ((d & 63) == 0) { red[d >> 6] = p0; red[4 + (d >> 6)] = p1; }
    __syncthreads();
    if (d == 0) {
        float r0 = red[0]+red[1]+red[2]+red[3] + db[0];
        float r1 = red[4]+red[5]+red[6]+red[7] + db[1];
        out[(size_t)n*2+0] = r0;           out[(size_t)n*2+1] = r1;
        out[2048 + (size_t)n*2+0] = r0;    out[2048 + (size_t)n*2+1] = r1;
        out[4096 + (size_t)n*2+0] = r0;    out[4096 + (size_t)n*2+1] = r1;
        if (n == 0) out[6144] = 0.f;
    }
}

extern "C" void kernel_launch(void* const* d_in, const int* in_sizes, int n_in,
                              void* d_out, int out_size, void* d_ws, size_t ws_size,
                              hipStream_t stream) {
    const float* x     = (const float*)d_in[0];
    const float* emb_w = (const float*)d_in[5];
    const float* emb_b = (const float*)d_in[6];
    const float* pe    = (const float*)d_in[7];
    const float* t_g1  = (const float*)d_in[11];
    const float* t_b1  = (const float*)d_in[12];
    const float* t_g2  = (const float*)d_in[13];
    const float* t_b2  = (const float*)d_in[14];
    const float* t_bb1 = (const float*)d_in[16];
    const float* t_bb2 = (const float*)d_in[18];
    const float* s_g1  = (const float*)d_in[22];
    const float* s_b1  = (const float*)d_in[23];
    const float* s_g2  = (const float*)d_in[24];
    const float* s_b2  = (const float*)d_in[25];
    const float* s_bb1 = (const float*)d_in[27];
    const float* s_bb2 = (const float*)d_in[29];
    const float* dec_w = (const float*)d_in[31];
    const float* dec_b = (const float*)d_in[32];
    float* out = (float*)d_out;

    // ---- workspace layout (~140 MB) ----
    float* F0 = (float*)d_ws;                       // 32 MB
    float* F1 = F0 + SZ;                            // 32 MB
    __hip_bfloat16* H0 = (__hip_bfloat16*)(F1 + SZ);// 16 MB each
    __hip_bfloat16* H1 = H0 + SZ;
    __hip_bfloat16* H2 = H1 + SZ;
    __hip_bfloat16* H3 = H2 + SZ;
    __hip_bfloat16* WT  = H3 + SZ;                  // 11 x 256x256
    __hip_bfloat16* WTE = WT + (size_t)11*DM*DM;    // 256x160
    __hip_bfloat16* XB  = WTE + (size_t)DM*160;     // 32768x160

    // ---- conversions ----
    cvtx_k<<<ROWS*160/256, 256, 0, stream>>>(x, XB);
    WPack wp;
    const int widx[11] = {8, 9, 10, 15, 17, 19, 20, 21, 26, 28, 30};
    for (int i = 0; i < 11; ++i) {
        wp.s[i] = (const float*)d_in[widx[i]];
        wp.d[i] = WT + (size_t)i*DM*DM;
    }
    cvtw_k<<<dim3(4, 4, 11), 256, 0, stream>>>(wp);
    cvte_k<<<DM, 192, 0, stream>>>(emb_w, WTE);

    dim3 gg(ROWS/128, 2);
    __hip_bfloat16* Wq  = WT;
    __hip_bfloat16* Wk  = WT + (size_t)1*DM*DM;
    __hip_bfloat16* Wv  = WT + (size_t)2*DM*DM;
    __hip_bfloat16* W1  = WT + (size_t)3*DM*DM;
    __hip_bfloat16* W2  = WT + (size_t)4*DM*DM;
    __hip_bfloat16* SWq = WT + (size_t)5*DM*DM;
    __hip_bfloat16* SWk = WT + (size_t)6*DM*DM;
    __hip_bfloat16* SWv = WT + (size_t)7*DM*DM;
    __hip_bfloat16* SW1 = WT + (size_t)8*DM*DM;
    __hip_bfloat16* SW2 = WT + (size_t)9*DM*DM;
    __hip_bfloat16* WTA = WT + (size_t)10*DM*DM;

    // ---- embed + PE (MFMA gemm, K=160) ----
    mgemm_k<<<gg, 256, 0, stream>>>(XB, 160, 5, WTE, 160, emb_b, pe, nullptr, F0, nullptr, 0);
    // ---- TAttention block ----
    ln_k<<<ROWS, 256, 0, stream>>>(F0, t_g1, t_b1, F1, H0);             // F1=xn, H0=xn(bf)
    mgemm_k<<<gg, 256, 0, stream>>>(H0, 256, 8, Wq, 256, nullptr, nullptr, nullptr, nullptr, H1, 0);
    mgemm_k<<<gg, 256, 0, stream>>>(H0, 256, 8, Wk, 256, nullptr, nullptr, nullptr, nullptr, H2, 0);
    mgemm_k<<<gg, 256, 0, stream>>>(H0, 256, 8, Wv, 256, nullptr, nullptr, nullptr, nullptr, H3, 0);
    attnT_k<<<dim3(4, NS), 256, 0, stream>>>(H1, H2, H3, F1);           // F1 = xn+att
    ln_k<<<ROWS, 256, 0, stream>>>(F1, t_g2, t_b2, F0, H0);             // F0=xt, H0=xt(bf)
    mgemm_k<<<gg, 256, 0, stream>>>(H0, 256, 8, W1, 256, t_bb1, nullptr, nullptr, nullptr, H1, 1);
    mgemm_k<<<gg, 256, 0, stream>>>(H1, 256, 8, W2, 256, t_bb2, nullptr, F0, F1, nullptr, 0);   // F1 = h1
    // ---- SAttention block ----
    ln_k<<<ROWS, 256, 0, stream>>>(F1, s_g1, s_b1, F0, H0);             // F0=xn2, H0=xn2(bf)
    mgemm_k<<<gg, 256, 0, stream>>>(H0, 256, 8, SWq, 256, nullptr, nullptr, nullptr, nullptr, H1, 0);
    mgemm_k<<<gg, 256, 0, stream>>>(H0, 256, 8, SWk, 256, nullptr, nullptr, nullptr, nullptr, H2, 0);
    mgemm_k<<<gg, 256, 0, stream>>>(H0, 256, 8, SWv, 256, nullptr, nullptr, nullptr, nullptr, H3, 0);
    attnS_k<<<dim3(8, 4, ST), 256, 0, stream>>>(H1, H2, H3, F0);        // F0 = xn2+att
    ln_k<<<ROWS, 256, 0, stream>>>(F0, s_g2, s_b2, F1, H0);             // F1=xt2, H0=xt2(bf)
    mgemm_k<<<gg, 256, 0, stream>>>(H0, 256, 8, SW1, 256, s_bb1, nullptr, nullptr, nullptr, H1, 1);
    mgemm_k<<<gg, 256, 0, stream>>>(H1, 256, 8, SW2, 256, s_bb2, nullptr, F1, F0, H2, 0);       // F0 = h2, H2 = h2(bf)
    // ---- temporal attention + decoder ----
    mgemm_k<<<gg, 256, 0, stream>>>(H2, 256, 8, WTA, 256, nullptr, nullptr, nullptr, F1, nullptr, 0);  // F1 = hh
    final_k<<<NS, 256, 0, stream>>>(F0, F1, dec_w, dec_b, out);
}

// Round 6
// 734.526 us; speedup vs baseline: 3.5103x; 1.0501x over previous
//
#include <hip/hip_runtime.h>
#include <hip/hip_bf16.h>
#include <math.h>

#define NS 1024
#define ST 32
#define DF 158
#define DM 256
#define KE 192                 // embed K padded to BK=64 multiple
#define ROWS (NS*ST)           // 32768
#define SZ ((size_t)ROWS*DM)   // 8388608 elems
#define LN_EPS 1e-5f
#define LOG2E 1.44269504088896f

typedef __attribute__((ext_vector_type(8)))  __bf16 bf16x8;
typedef __attribute__((ext_vector_type(16))) float  f32x16;

__device__ __forceinline__ float wave_sum(float v) {
#pragma unroll
    for (int o = 32; o > 0; o >>= 1) v += __shfl_xor(v, o);
    return v;
}

__device__ __forceinline__ unsigned pkbf(float a, float b) {
    __hip_bfloat16 ha = __float2bfloat16(a), hb = __float2bfloat16(b);
    unsigned short ua, ub;
    __builtin_memcpy(&ua, &ha, 2); __builtin_memcpy(&ub, &hb, 2);
    return (unsigned)ua | ((unsigned)ub << 16);
}

// ================= conversion kernels (run every launch; idempotent) =========
__global__ __launch_bounds__(256) void cvtx_k(const float* __restrict__ x,
        __hip_bfloat16* __restrict__ xb) {
    int idx = blockIdx.x*256 + threadIdx.x;          // < 32768*192
    int r = idx / KE, c = idx - r*KE;
    float v = (c < DF) ? x[(size_t)r*DF + c] : 0.f;
    xb[idx] = __float2bfloat16(v);
}

struct WPack { const float* s[11]; __hip_bfloat16* d[11]; };

__global__ __launch_bounds__(256) void cvtw_k(WPack wp) {
    const float* W = wp.s[blockIdx.z];
    __hip_bfloat16* Wt = wp.d[blockIdx.z];
    __shared__ float t[64][65];
    int bi = blockIdx.x*64, bj = blockIdx.y*64;
    int r = threadIdx.x >> 2, c0 = (threadIdx.x & 3) * 16;
#pragma unroll
    for (int i = 0; i < 16; i += 4) {
        float4 v = *(const float4*)(W + (size_t)(bi + r)*DM + bj + c0 + i);
        t[r][c0+i+0] = v.x; t[r][c0+i+1] = v.y;
        t[r][c0+i+2] = v.z; t[r][c0+i+3] = v.w;
    }
    __syncthreads();
    unsigned u[8];
#pragma unroll
    for (int i = 0; i < 8; ++i) u[i] = pkbf(t[c0+2*i][r], t[c0+2*i+1][r]);
    __hip_bfloat16* op = Wt + (size_t)(bj + r)*DM + bi + c0;
    *(uint4*)(op)     = make_uint4(u[0], u[1], u[2], u[3]);
    *(uint4*)(op + 8) = make_uint4(u[4], u[5], u[6], u[7]);
}

__global__ __launch_bounds__(192) void cvte_k(const float* __restrict__ W,
        __hip_bfloat16* __restrict__ Wt) {
    int n = blockIdx.x, t = threadIdx.x;   // t < 192
    float v = (t < DF) ? W[(size_t)t*DM + n] : 0.f;
    Wt[(size_t)n*KE + t] = __float2bfloat16(v);
}

// ================= LayerNorm: one wave per row, no barriers ==================
__global__ __launch_bounds__(256) void ln_k(const float* __restrict__ a,
        const float* __restrict__ g, const float* __restrict__ be,
        float* __restrict__ out, __hip_bfloat16* __restrict__ outb) {
    int w = threadIdx.x >> 6, lane = threadIdx.x & 63;
    size_t r = (size_t)blockIdx.x*4 + w;
    const float* ar = a + r*DM + lane*4;
    float4 v = *(const float4*)(ar);
    float mu = wave_sum(v.x+v.y+v.z+v.w) * (1.0f/DM);
    float4 c = make_float4(v.x-mu, v.y-mu, v.z-mu, v.w-mu);
    float var = wave_sum(c.x*c.x + c.y*c.y + c.z*c.z + c.w*c.w) * (1.0f/DM);
    float rs = rsqrtf(var + LN_EPS);
    float4 g4 = *(const float4*)(g + lane*4);
    float4 b4 = *(const float4*)(be + lane*4);
    float4 o = make_float4(c.x*rs*g4.x + b4.x, c.y*rs*g4.y + b4.y,
                           c.z*rs*g4.z + b4.z, c.w*rs*g4.w + b4.w);
    *(float4*)(out + r*DM + lane*4) = o;
    *(uint2*)(outb + r*DM + lane*4) = make_uint2(pkbf(o.x, o.y), pkbf(o.z, o.w));
}

// ================= MFMA GEMM: C[M,256] = A[M,K]@W[K,256] =====================
// fmt: 0 = std [row][col]; 1 = sfmt [(t*4+h)][stock][d]; 2 = tfmt [h][stock][t][d]
__global__ __launch_bounds__(256) void mgemm_k(const __hip_bfloat16* __restrict__ A,
        int sA, int nk, const __hip_bfloat16* __restrict__ Wt, int sW,
        const float* __restrict__ bias, const float* __restrict__ pe,
        const float* __restrict__ resid, float* __restrict__ Cf,
        __hip_bfloat16* __restrict__ Cb, int relu, int fmt, float scale) {
    __shared__ __hip_bfloat16 As[128*72];
    __shared__ __hip_bfloat16 Ws[128*72];
    const int tid = threadIdx.x;
    const int w = tid >> 6, lane = tid & 63;
    const int uh = lane >> 5, l31 = lane & 31;
    const int wm = (w >> 1)*64, wn = (w & 1)*64;
    const size_t m0 = (size_t)blockIdx.x*128;
    const int n0 = blockIdx.y*128;

    f32x16 acc[2][2];
#pragma unroll
    for (int mt = 0; mt < 2; ++mt)
#pragma unroll
        for (int nt = 0; nt < 2; ++nt)
#pragma unroll
            for (int r = 0; r < 16; ++r) acc[mt][nt][r] = 0.f;

    // staging: 128 rows x 64 k per matrix; thread -> row tid>>1, 32-col half
    const int lr = tid >> 1, lcb = (tid & 1)*32;
    const __hip_bfloat16* ap = A  + (m0 + lr)*sA + lcb;
    const __hip_bfloat16* wp = Wt + (size_t)(n0 + lr)*sW + lcb;
    uint4 pa0 = *(const uint4*)(ap),      pa1 = *(const uint4*)(ap + 8);
    uint4 pa2 = *(const uint4*)(ap + 16), pa3 = *(const uint4*)(ap + 24);
    uint4 pw0 = *(const uint4*)(wp),      pw1 = *(const uint4*)(wp + 8);
    uint4 pw2 = *(const uint4*)(wp + 16), pw3 = *(const uint4*)(wp + 24);
    for (int kt = 0; kt < nk; ++kt) {
        __syncthreads();
        *(uint4*)&As[lr*72 + lcb]      = pa0;
        *(uint4*)&As[lr*72 + lcb + 8]  = pa1;
        *(uint4*)&As[lr*72 + lcb + 16] = pa2;
        *(uint4*)&As[lr*72 + lcb + 24] = pa3;
        *(uint4*)&Ws[lr*72 + lcb]      = pw0;
        *(uint4*)&Ws[lr*72 + lcb + 8]  = pw1;
        *(uint4*)&Ws[lr*72 + lcb + 16] = pw2;
        *(uint4*)&Ws[lr*72 + lcb + 24] = pw3;
        __syncthreads();
        if (kt + 1 < nk) {
            int ko = (kt + 1)*64;
            pa0 = *(const uint4*)(ap + ko);      pa1 = *(const uint4*)(ap + ko + 8);
            pa2 = *(const uint4*)(ap + ko + 16); pa3 = *(const uint4*)(ap + ko + 24);
            pw0 = *(const uint4*)(wp + ko);      pw1 = *(const uint4*)(wp + ko + 8);
            pw2 = *(const uint4*)(wp + ko + 16); pw3 = *(const uint4*)(wp + ko + 24);
        }
#pragma unroll
        for (int ks = 0; ks < 4; ++ks) {
            bf16x8 a0 = *(const bf16x8*)&As[(wm + l31)*72      + ks*16 + uh*8];
            bf16x8 a1 = *(const bf16x8*)&As[(wm + 32 + l31)*72 + ks*16 + uh*8];
            bf16x8 b0 = *(const bf16x8*)&Ws[(wn + l31)*72      + ks*16 + uh*8];
            bf16x8 b1 = *(const bf16x8*)&Ws[(wn + 32 + l31)*72 + ks*16 + uh*8];
            acc[0][0] = __builtin_amdgcn_mfma_f32_32x32x16_bf16(a0, b0, acc[0][0], 0, 0, 0);
            acc[0][1] = __builtin_amdgcn_mfma_f32_32x32x16_bf16(a0, b1, acc[0][1], 0, 0, 0);
            acc[1][0] = __builtin_amdgcn_mfma_f32_32x32x16_bf16(a1, b0, acc[1][0], 0, 0, 0);
            acc[1][1] = __builtin_amdgcn_mfma_f32_32x32x16_bf16(a1, b1, acc[1][1], 0, 0, 0);
        }
    }

#pragma unroll
    for (int nt = 0; nt < 2; ++nt) {
        int colg = n0 + wn + nt*32 + l31;
        float bz = bias ? bias[colg] : 0.f;
#pragma unroll
        for (int mt = 0; mt < 2; ++mt) {
#pragma unroll
            for (int r = 0; r < 16; ++r) {
                size_t mg = m0 + wm + mt*32 + (r & 3) + ((r >> 2) << 3) + 4*uh;
                float v = (acc[mt][nt][r] + bz) * scale;
                if (pe)    v += pe[(mg & 31)*DM + colg];
                if (relu)  v = fmaxf(v, 0.f);
                if (resid) v += resid[mg*DM + colg];
                size_t oidx;
                if (fmt == 1)
                    oidx = (size_t)((mg & 31)*4 + (colg >> 6))*65536 + (mg >> 5)*64 + (colg & 63);
                else if (fmt == 2)
                    oidx = ((size_t)(colg >> 6)*NS + (mg >> 5))*2048 + (mg & 31)*64 + (colg & 63);
                else
                    oidx = mg*DM + colg;
                if (Cf) Cf[oidx] = v;
                if (Cb) Cb[oidx] = __float2bfloat16(v);
            }
        }
    }
}

// ================= T-attention: MFMA, one wave per head, tfmt QKV ============
// Q pre-scaled by log2e in its gemm. No-max softmax (scores O(+-5), exp2-safe).
union __align__(16) WLds { __hip_bfloat16 vt[64*40]; float ob[32*68]; };

__global__ __launch_bounds__(256) void attnT_k(const __hip_bfloat16* __restrict__ Q,
        const __hip_bfloat16* __restrict__ K, const __hip_bfloat16* __restrict__ V,
        float* __restrict__ O) {
    __shared__ WLds sm4[4];
    const int n = blockIdx.x;
    const int w = threadIdx.x >> 6, lane = threadIdx.x & 63;
    const int uh = lane >> 5, l31 = lane & 31;
    const size_t base = ((size_t)w*NS + n)*2048;   // head w, stock n

    // K (A-op) and Q^T (B-op) fragments straight from global
    bf16x8 kf[4], qf[4];
#pragma unroll
    for (int s = 0; s < 4; ++s) {
        kf[s] = *(const bf16x8*)(K + base + l31*64 + s*16 + uh*8);
        qf[s] = *(const bf16x8*)(Q + base + l31*64 + s*16 + uh*8);
    }
    // stage V transposed into per-wave LDS: Vt[d][t], stride 40
    __hip_bfloat16* vt = sm4[w].vt;
#pragma unroll
    for (int i = 0; i < 2; ++i) {
        int c = lane*2 + i;
        int dg = c >> 3, tg = c & 7;           // dg 0..15, tg 0..7
        const ushort* vp = (const ushort*)(V + base + (tg*4)*64 + dg*4);
        ushort4 s0 = *(const ushort4*)(vp);
        ushort4 s1 = *(const ushort4*)(vp + 64);
        ushort4 s2 = *(const ushort4*)(vp + 128);
        ushort4 s3 = *(const ushort4*)(vp + 192);
        *(uint2*)&vt[(dg*4+0)*40 + tg*4] = make_uint2((unsigned)s0.x | ((unsigned)s1.x<<16),
                                                      (unsigned)s2.x | ((unsigned)s3.x<<16));
        *(uint2*)&vt[(dg*4+1)*40 + tg*4] = make_uint2((unsigned)s0.y | ((unsigned)s1.y<<16),
                                                      (unsigned)s2.y | ((unsigned)s3.y<<16));
        *(uint2*)&vt[(dg*4+2)*40 + tg*4] = make_uint2((unsigned)s0.z | ((unsigned)s1.z<<16),
                                                      (unsigned)s2.z | ((unsigned)s3.z<<16));
        *(uint2*)&vt[(dg*4+3)*40 + tg*4] = make_uint2((unsigned)s0.w | ((unsigned)s1.w<<16),
                                                      (unsigned)s2.w | ((unsigned)s3.w<<16));
    }

    // S^T = K * Q^T  (32tk x 32tq), k = hd = 64
    f32x16 sa;
#pragma unroll
    for (int r = 0; r < 16; ++r) sa[r] = 0.f;
    sa = __builtin_amdgcn_mfma_f32_32x32x16_bf16(kf[0], qf[0], sa, 0, 0, 0);
    sa = __builtin_amdgcn_mfma_f32_32x32x16_bf16(kf[1], qf[1], sa, 0, 0, 0);
    sa = __builtin_amdgcn_mfma_f32_32x32x16_bf16(kf[2], qf[2], sa, 0, 0, 0);
    sa = __builtin_amdgcn_mfma_f32_32x32x16_bf16(kf[3], qf[3], sa, 0, 0, 0);

    // softmax over tk (column = tq = l31, split across uh halves)
    float p[16], l = 0.f;
#pragma unroll
    for (int r = 0; r < 16; ++r) { p[r] = exp2f(sa[r]); l += p[r]; }
    l += __shfl_xor(l, 32);

    // P^T B-fragments (k = 32): 2 frags via xor-32 exchange
    bf16x8 pf[2];
#pragma unroll
    for (int s = 0; s < 2; ++s) {
        unsigned A0 = pkbf(p[8*s+0], p[8*s+1]);
        unsigned A1 = pkbf(p[8*s+2], p[8*s+3]);
        unsigned B0 = pkbf(p[8*s+4], p[8*s+5]);
        unsigned B1 = pkbf(p[8*s+6], p[8*s+7]);
        unsigned xA0 = (unsigned)__shfl_xor((int)A0, 32);
        unsigned xA1 = (unsigned)__shfl_xor((int)A1, 32);
        unsigned xB0 = (unsigned)__shfl_xor((int)B0, 32);
        unsigned xB1 = (unsigned)__shfl_xor((int)B1, 32);
        union { uint4 i; bf16x8 v; } cv;
        cv.i = make_uint4(uh ? xB0 : A0, uh ? xB1 : A1,
                          uh ? B0 : xA0, uh ? B1 : xA1);
        pf[s] = cv.v;
    }

    // O^T = V^T * P^T : 2 d-tiles, k = 32
    f32x16 oa[2];
#pragma unroll
    for (int c = 0; c < 2; ++c) {
#pragma unroll
        for (int r = 0; r < 16; ++r) oa[c][r] = 0.f;
        bf16x8 v0 = *(const bf16x8*)&vt[(c*32 + l31)*40 + uh*8];
        bf16x8 v1 = *(const bf16x8*)&vt[(c*32 + l31)*40 + 16 + uh*8];
        oa[c] = __builtin_amdgcn_mfma_f32_32x32x16_bf16(v0, pf[0], oa[c], 0, 0, 0);
        oa[c] = __builtin_amdgcn_mfma_f32_32x32x16_bf16(v1, pf[1], oa[c], 0, 0, 0);
    }

    // epilogue: transpose via per-wave LDS, fused residual RMW (std layout)
    float invl = 1.0f / l;
    float* ob = sm4[w].ob;
#pragma unroll
    for (int c = 0; c < 2; ++c)
#pragma unroll
        for (int r = 0; r < 16; ++r) {
            int d = (r & 3) + ((r >> 2) << 3) + 4*uh + 32*c;
            ob[l31*68 + d] = oa[c][r] * invl;
        }
    int t = lane >> 1, d0 = (lane & 1)*32;
    float* gp = O + ((size_t)n*ST + t)*DM + w*64 + d0;
#pragma unroll
    for (int i = 0; i < 8; ++i) {
        float4 prev = *(const float4*)(gp + 4*i);
        float4 nv = *(const float4*)&ob[t*68 + d0 + 4*i];
        *(float4*)(gp + 4*i) = make_float4(prev.x+nv.x, prev.y+nv.y, prev.z+nv.z, prev.w+nv.w);
    }
}

// ================= S-attention: MFMA flash, sfmt QKV, no-max exp2 ============
union __align__(16) LdsS {
    struct { __hip_bfloat16 K[64*72]; __hip_bfloat16 Vt[64*72]; } s;
    float Ob[4][32*68];
};

__global__ __launch_bounds__(256) void attnS_k(const __hip_bfloat16* __restrict__ Qb,
        const __hip_bfloat16* __restrict__ Kb, const __hip_bfloat16* __restrict__ Vb,
        float* __restrict__ O) {
    __shared__ LdsS sm;
    const int qt = blockIdx.x, h = blockIdx.y, tt = blockIdx.z;
    const int tid = threadIdx.x;
    const int w = tid >> 6, lane = tid & 63;
    const int uh = lane >> 5, l31 = lane & 31;
    const size_t hb = (size_t)(tt*4 + h)*65536;   // sfmt slice base

    // Q^T B-fragments straight from global (contiguous 64-elem rows)
    bf16x8 qf[4];
    {
        const __hip_bfloat16* qp = Qb + hb + (size_t)(qt*128 + w*32 + l31)*64 + 8*uh;
        qf[0] = *(const bf16x8*)(qp);
        qf[1] = *(const bf16x8*)(qp + 16);
        qf[2] = *(const bf16x8*)(qp + 32);
        qf[3] = *(const bf16x8*)(qp + 48);
    }

    f32x16 oa[2];
#pragma unroll
    for (int c = 0; c < 2; ++c)
#pragma unroll
        for (int r = 0; r < 16; ++r) oa[c][r] = 0.f;
    float lrun = 0.f;

    for (int kt = 0; kt < 16; ++kt) {
        __syncthreads();
        // stage K row-major (8 KB contiguous tile)
        {
            const __hip_bfloat16* kb = Kb + hb + (size_t)kt*4096;
#pragma unroll
            for (int i = 0; i < 2; ++i) {
                int c = tid*2 + i;
                int j = c >> 3, col = (c & 7)*8;
                *(uint4*)&sm.s.K[j*72 + col] = *(const uint4*)(kb + c*8);
            }
        }
        // stage V transposed
        {
            int j0 = (tid & 15)*4, cb = (tid >> 4)*4;
            const ushort* vp = (const ushort*)(Vb + hb + (size_t)(kt*64 + j0)*64 + cb);
            ushort4 s0 = *(const ushort4*)(vp);
            ushort4 s1 = *(const ushort4*)(vp + 64);
            ushort4 s2 = *(const ushort4*)(vp + 128);
            ushort4 s3 = *(const ushort4*)(vp + 192);
            *(uint2*)&sm.s.Vt[(cb+0)*72 + j0] = make_uint2((unsigned)s0.x | ((unsigned)s1.x<<16),
                                                           (unsigned)s2.x | ((unsigned)s3.x<<16));
            *(uint2*)&sm.s.Vt[(cb+1)*72 + j0] = make_uint2((unsigned)s0.y | ((unsigned)s1.y<<16),
                                                           (unsigned)s2.y | ((unsigned)s3.y<<16));
            *(uint2*)&sm.s.Vt[(cb+2)*72 + j0] = make_uint2((unsigned)s0.z | ((unsigned)s1.z<<16),
                                                           (unsigned)s2.z | ((unsigned)s3.z<<16));
            *(uint2*)&sm.s.Vt[(cb+3)*72 + j0] = make_uint2((unsigned)s0.w | ((unsigned)s1.w<<16),
                                                           (unsigned)s2.w | ((unsigned)s3.w<<16));
        }
        __syncthreads();

        // S^T = K * Q^T : 2 x (32x32), chained over hd=64 (Q pre-scaled)
        f32x16 sa[2];
#pragma unroll
        for (int ct = 0; ct < 2; ++ct) {
            f32x16 a2;
#pragma unroll
            for (int r = 0; r < 16; ++r) a2[r] = 0.f;
            const __hip_bfloat16* kb = &sm.s.K[(ct*32 + l31)*72 + 8*uh];
            a2 = __builtin_amdgcn_mfma_f32_32x32x16_bf16(*(const bf16x8*)(kb +  0), qf[0], a2, 0, 0, 0);
            a2 = __builtin_amdgcn_mfma_f32_32x32x16_bf16(*(const bf16x8*)(kb + 16), qf[1], a2, 0, 0, 0);
            a2 = __builtin_amdgcn_mfma_f32_32x32x16_bf16(*(const bf16x8*)(kb + 32), qf[2], a2, 0, 0, 0);
            a2 = __builtin_amdgcn_mfma_f32_32x32x16_bf16(*(const bf16x8*)(kb + 48), qf[3], a2, 0, 0, 0);
            sa[ct] = a2;
        }

        // no-max softmax accumulation: p = exp2(score'), l += sum
        float p[32];
        float rs = 0.f;
#pragma unroll
        for (int ct = 0; ct < 2; ++ct)
#pragma unroll
            for (int r = 0; r < 16; ++r) {
                float e = exp2f(sa[ct][r]);
                p[ct*16 + r] = e;
                rs += e;
            }
        rs += __shfl_xor(rs, 32);
        lrun += rs;

        // P^T B-fragments from registers + xor-32 shuffles
        bf16x8 bfr[4];
#pragma unroll
        for (int s = 0; s < 4; ++s) {
            int ct = s >> 1, b = (s & 1) << 3;
            unsigned A0 = pkbf(p[ct*16+b+0], p[ct*16+b+1]);
            unsigned A1 = pkbf(p[ct*16+b+2], p[ct*16+b+3]);
            unsigned B0 = pkbf(p[ct*16+b+4], p[ct*16+b+5]);
            unsigned B1 = pkbf(p[ct*16+b+6], p[ct*16+b+7]);
            unsigned xA0 = (unsigned)__shfl_xor((int)A0, 32);
            unsigned xA1 = (unsigned)__shfl_xor((int)A1, 32);
            unsigned xB0 = (unsigned)__shfl_xor((int)B0, 32);
            unsigned xB1 = (unsigned)__shfl_xor((int)B1, 32);
            union { uint4 i; bf16x8 v; } cv;
            cv.i = make_uint4(uh ? xB0 : A0, uh ? xB1 : A1,
                              uh ? B0 : xA0, uh ? B1 : xA1);
            bfr[s] = cv.v;
        }

        // O^T += V^T * P^T
#pragma unroll
        for (int c = 0; c < 2; ++c) {
            const __hip_bfloat16* vb = &sm.s.Vt[(c*32 + l31)*72 + 8*uh];
            oa[c] = __builtin_amdgcn_mfma_f32_32x32x16_bf16(*(const bf16x8*)(vb +  0), bfr[0], oa[c], 0, 0, 0);
            oa[c] = __builtin_amdgcn_mfma_f32_32x32x16_bf16(*(const bf16x8*)(vb + 16), bfr[1], oa[c], 0, 0, 0);
            oa[c] = __builtin_amdgcn_mfma_f32_32x32x16_bf16(*(const bf16x8*)(vb + 32), bfr[2], oa[c], 0, 0, 0);
            oa[c] = __builtin_amdgcn_mfma_f32_32x32x16_bf16(*(const bf16x8*)(vb + 48), bfr[3], oa[c], 0, 0, 0);
        }
    }

    // epilogue: transpose O^T via LDS, fused residual RMW, std layout out
    __syncthreads();
    float invl = 1.0f / lrun;
    float* ob = sm.Ob[w];
#pragma unroll
    for (int c = 0; c < 2; ++c)
#pragma unroll
        for (int r = 0; r < 16; ++r) {
            int d = (r & 3) + ((r >> 2) << 3) + 4*uh + 32*c;
            ob[l31*68 + d] = oa[c][r] * invl;
        }
#pragma unroll
    for (int pp = 0; pp < 2; ++pp) {
        int qr = pp*16 + (lane >> 2);
        int dc = (lane & 3) << 4;
        float* gp = O + ((size_t)(qt*128 + w*32 + qr)*ST + tt)*DM + h*64 + dc;
#pragma unroll
        for (int i = 0; i < 4; ++i) {
            float4 prev = *(const float4*)(gp + 4*i);
            float4 nv = *(const float4*)&ob[qr*68 + dc + 4*i];
            *(float4*)(gp + 4*i) = make_float4(prev.x+nv.x, prev.y+nv.y,
                                               prev.z+nv.z, prev.w+nv.w);
        }
    }
}

// ================= temporal pooling + decoder ================================
__global__ __launch_bounds__(256) void final_k(const float* __restrict__ H,
        const float* __restrict__ HH, const float* __restrict__ dw,
        const float* __restrict__ db, float* __restrict__ out) {
    int n = blockIdx.x, d = threadIdx.x;
    int w = d >> 6, lane = d & 63;
    __shared__ float lam[ST];
    __shared__ float red[8];
    const float* hh = HH + (size_t)n*ST*DM;
    float4 qd = *(const float4*)(hh + 31*DM + lane*4);
#pragma unroll
    for (int i = 0; i < 8; ++i) {
        int t = w*8 + i;
        float4 h4 = *(const float4*)(hh + t*DM + lane*4);
        float s = wave_sum(h4.x*qd.x + h4.y*qd.y + h4.z*qd.z + h4.w*qd.w);
        if (lane == 0) lam[t] = s;
    }
    __syncthreads();
    float mx = -1e30f;
#pragma unroll
    for (int t = 0; t < ST; ++t) mx = fmaxf(mx, lam[t]);
    float sum = 0.f;
#pragma unroll
    for (int t = 0; t < ST; ++t) sum += __expf(lam[t]-mx);
    float acc = 0.f;
    const float* hrow = H + (size_t)n*ST*DM;
#pragma unroll
    for (int t = 0; t < ST; ++t) acc += __expf(lam[t]-mx) * hrow[t*DM + d];
    acc /= sum;
    float p0 = wave_sum(acc * dw[2*d+0]);
    float p1 = wave_sum(acc * dw[2*d+1]);
    if (lane == 0) { red[w] = p0; red[4 + w] = p1; }
    __syncthreads();
    if (d == 0) {
        float r0 = red[0]+red[1]+red[2]+red[3] + db[0];
        float r1 = red[4]+red[5]+red[6]+red[7] + db[1];
        out[(size_t)n*2+0] = r0;           out[(size_t)n*2+1] = r1;
        out[2048 + (size_t)n*2+0] = r0;    out[2048 + (size_t)n*2+1] = r1;
        out[4096 + (size_t)n*2+0] = r0;    out[4096 + (size_t)n*2+1] = r1;
        if (n == 0) out[6144] = 0.f;
    }
}

extern "C" void kernel_launch(void* const* d_in, const int* in_sizes, int n_in,
                              void* d_out, int out_size, void* d_ws, size_t ws_size,
                              hipStream_t stream) {
    const float* x     = (const float*)d_in[0];
    const float* emb_w = (const float*)d_in[5];
    const float* emb_b = (const float*)d_in[6];
    const float* pe    = (const float*)d_in[7];
    const float* t_g1  = (const float*)d_in[11];
    const float* t_b1  = (const float*)d_in[12];
    const float* t_g2  = (const float*)d_in[13];
    const float* t_b2  = (const float*)d_in[14];
    const float* t_bb1 = (const float*)d_in[16];
    const float* t_bb2 = (const float*)d_in[18];
    const float* s_g1  = (const float*)d_in[22];
    const float* s_b1  = (const float*)d_in[23];
    const float* s_g2  = (const float*)d_in[24];
    const float* s_b2  = (const float*)d_in[25];
    const float* s_bb1 = (const float*)d_in[27];
    const float* s_bb2 = (const float*)d_in[29];
    const float* dec_w = (const float*)d_in[31];
    const float* dec_b = (const float*)d_in[32];
    float* out = (float*)d_out;

    // ---- workspace layout (~143 MB) ----
    float* F0 = (float*)d_ws;                       // 32 MB
    float* F1 = F0 + SZ;                            // 32 MB
    __hip_bfloat16* H0 = (__hip_bfloat16*)(F1 + SZ);// 16 MB each
    __hip_bfloat16* H1 = H0 + SZ;
    __hip_bfloat16* H2 = H1 + SZ;
    __hip_bfloat16* H3 = H2 + SZ;
    __hip_bfloat16* WT  = H3 + SZ;                  // 11 x 256x256
    __hip_bfloat16* WTE = WT + (size_t)11*DM*DM;    // 256x192
    __hip_bfloat16* XB  = WTE + (size_t)DM*KE;      // 32768x192

    // ---- conversions ----
    cvtx_k<<<ROWS*KE/256, 256, 0, stream>>>(x, XB);
    WPack wp;
    const int widx[11] = {8, 9, 10, 15, 17, 19, 20, 21, 26, 28, 30};
    for (int i = 0; i < 11; ++i) {
        wp.s[i] = (const float*)d_in[widx[i]];
        wp.d[i] = WT + (size_t)i*DM*DM;
    }
    cvtw_k<<<dim3(4, 4, 11), 256, 0, stream>>>(wp);
    cvte_k<<<DM, 192, 0, stream>>>(emb_w, WTE);

    dim3 gg(ROWS/128, 2);
    __hip_bfloat16* Wq  = WT;
    __hip_bfloat16* Wk  = WT + (size_t)1*DM*DM;
    __hip_bfloat16* Wv  = WT + (size_t)2*DM*DM;
    __hip_bfloat16* W1  = WT + (size_t)3*DM*DM;
    __hip_bfloat16* W2  = WT + (size_t)4*DM*DM;
    __hip_bfloat16* SWq = WT + (size_t)5*DM*DM;
    __hip_bfloat16* SWk = WT + (size_t)6*DM*DM;
    __hip_bfloat16* SWv = WT + (size_t)7*DM*DM;
    __hip_bfloat16* SW1 = WT + (size_t)8*DM*DM;
    __hip_bfloat16* SW2 = WT + (size_t)9*DM*DM;
    __hip_bfloat16* WTA = WT + (size_t)10*DM*DM;

    // ---- embed + PE (MFMA gemm, K=192 padded) ----
    mgemm_k<<<gg, 256, 0, stream>>>(XB, KE, 3, WTE, KE, emb_b, pe, nullptr, F0, nullptr, 0, 0, 1.f);
    // ---- TAttention block ----
    ln_k<<<ROWS/4, 256, 0, stream>>>(F0, t_g1, t_b1, F1, H0);            // F1=xn, H0=xn(bf)
    mgemm_k<<<gg, 256, 0, stream>>>(H0, 256, 4, Wq, 256, nullptr, nullptr, nullptr, nullptr, H1, 0, 2, LOG2E);
    mgemm_k<<<gg, 256, 0, stream>>>(H0, 256, 4, Wk, 256, nullptr, nullptr, nullptr, nullptr, H2, 0, 2, 1.f);
    mgemm_k<<<gg, 256, 0, stream>>>(H0, 256, 4, Wv, 256, nullptr, nullptr, nullptr, nullptr, H3, 0, 2, 1.f);
    attnT_k<<<NS, 256, 0, stream>>>(H1, H2, H3, F1);                     // F1 = xn+att
    ln_k<<<ROWS/4, 256, 0, stream>>>(F1, t_g2, t_b2, F0, H0);            // F0=xt, H0=xt(bf)
    mgemm_k<<<gg, 256, 0, stream>>>(H0, 256, 4, W1, 256, t_bb1, nullptr, nullptr, nullptr, H1, 1, 0, 1.f);
    mgemm_k<<<gg, 256, 0, stream>>>(H1, 256, 4, W2, 256, t_bb2, nullptr, F0, F1, nullptr, 0, 0, 1.f);   // F1 = h1
    // ---- SAttention block ----
    ln_k<<<ROWS/4, 256, 0, stream>>>(F1, s_g1, s_b1, F0, H0);            // F0=xn2, H0=xn2(bf)
    mgemm_k<<<gg, 256, 0, stream>>>(H0, 256, 4, SWq, 256, nullptr, nullptr, nullptr, nullptr, H1, 0, 1, 0.125f*LOG2E);
    mgemm_k<<<gg, 256, 0, stream>>>(H0, 256, 4, SWk, 256, nullptr, nullptr, nullptr, nullptr, H2, 0, 1, 1.f);
    mgemm_k<<<gg, 256, 0, stream>>>(H0, 256, 4, SWv, 256, nullptr, nullptr, nullptr, nullptr, H3, 0, 1, 1.f);
    attnS_k<<<dim3(8, 4, ST), 256, 0, stream>>>(H1, H2, H3, F0);         // F0 = xn2+att
    ln_k<<<ROWS/4, 256, 0, stream>>>(F0, s_g2, s_b2, F1, H0);            // F1=xt2, H0=xt2(bf)
    mgemm_k<<<gg, 256, 0, stream>>>(H0, 256, 4, SW1, 256, s_bb1, nullptr, nullptr, nullptr, H1, 1, 0, 1.f);
    mgemm_k<<<gg, 256, 0, stream>>>(H1, 256, 4, SW2, 256, s_bb2, nullptr, F1, F0, H2, 0, 0, 1.f);       // F0=h2, H2=h2(bf)
    // ---- temporal attention + decoder ----
    mgemm_k<<<gg, 256, 0, stream>>>(H2, 256, 4, WTA, 256, nullptr, nullptr, nullptr, F1, nullptr, 0, 0, 1.f);  // F1 = hh
    final_k<<<NS, 256, 0, stream>>>(F0, F1, dec_w, dec_b, out);
}